// Round 7
// baseline (225.891 us; speedup 1.0000x reference)
//
#include <hip/hip_runtime.h>
#include <stdint.h>

typedef __attribute__((ext_vector_type(4))) float f32x4;
typedef __attribute__((ext_vector_type(8))) short bf16x8;
typedef __attribute__((ext_vector_type(8))) unsigned short u16x8;
typedef __attribute__((ext_vector_type(4))) unsigned short u16x4;

#define NPIX 100352      // 32*56*56
#define CDIM 256
#define QKVN 768
#define HWDIM 56

__device__ __forceinline__ unsigned short f2bf(float f) {
  union { float f; unsigned int u; } cv; cv.f = f;
  unsigned int u = cv.u;
  unsigned int r = (u + 0x7FFFu + ((u >> 16) & 1u)) >> 16;
  return (unsigned short)r;
}
__device__ __forceinline__ float bf2f(unsigned short h) {
  union { unsigned int u; float f; } cv; cv.u = ((unsigned int)h) << 16;
  return cv.f;
}

// ---------------- fp32 -> bf16 convert (8 elems/thread) ----------------
__global__ __launch_bounds__(256) void cvt_kernel(const float* __restrict__ in,
                                                  unsigned short* __restrict__ out,
                                                  int n8) {
  int i = blockIdx.x * 256 + threadIdx.x;
  if (i >= n8) return;
  const float4* p = reinterpret_cast<const float4*>(in) + (size_t)i * 2;
  float4 a = p[0], b = p[1];
  u16x8 r;
  r[0] = f2bf(a.x); r[1] = f2bf(a.y); r[2] = f2bf(a.z); r[3] = f2bf(a.w);
  r[4] = f2bf(b.x); r[5] = f2bf(b.y); r[6] = f2bf(b.z); r[7] = f2bf(b.w);
  *(reinterpret_cast<u16x8*>(out) + i) = r;
}

// ---------------- bias+mask table precompute ----------------
// layout: [cls][head][jf][c2][q][fr][r] bf16 -> lane (q,fr) loads u16x4 per (jf,c2)
__global__ __launch_bounds__(256) void bias_pre(const float* __restrict__ table,
                                                unsigned short* __restrict__ bt) {
  int e = blockIdx.x * 256 + threadIdx.x;       // 131072 total
  int r  = e & 3;
  int fr = (e >> 2) & 15;
  int q  = (e >> 6) & 3;
  int c2 = (e >> 8) & 3;
  int jf = (e >> 10) & 3;
  int h  = (e >> 12) & 7;
  int cls = (e >> 15) & 3;
  int j = jf * 16 + q * 4 + r;
  int i = c2 * 16 + fr;
  float v;
  if (j > 48 || i > 48) {
    v = -1e30f;
  } else {
    int bh = cls >> 1, bw = cls & 1;
    int iwi = i / 7, iwj = i % 7;
    int jwi = j / 7, jwj = j % 7;
    int ireg = (bh ? ((iwi < 4) ? 1 : 2) : 0) * 3 + (bw ? ((iwj < 4) ? 1 : 2) : 0);
    int jreg = (bh ? ((jwi < 4) ? 1 : 2) : 0) * 3 + (bw ? ((jwj < 4) ? 1 : 2) : 0);
    float m = (ireg == jreg) ? 0.f : -100.f;
    v = table[((iwi - jwi + 6) * 13 + (iwj - jwj + 6)) * 8 + h] + m;
  }
  bt[e] = f2bf(v);
}

// ---------------- bf16 MFMA GEMM: C[M,N] = A[M,K] * Bt[N,K]^T + bias ----------------
// A_F32: A is fp32, converted to bf16 in-register during staging (fused cvt).
// Transposed-D epilogue: mfma(b, a) so reg axis runs along N -> vector stores.
__device__ __forceinline__ void gload16(const unsigned short* g, unsigned short* l) {
  __builtin_amdgcn_global_load_lds((const __attribute__((address_space(1))) void*)g,
                                   (__attribute__((address_space(3))) void*)l, 16, 0, 0);
}

template<bool A_F32, bool OUT_BF16>
__global__ __launch_bounds__(256) void gemm_kernel(
    const void* __restrict__ Ain,
    const unsigned short* __restrict__ Bt,
    const float* __restrict__ bias,
    void* __restrict__ out,
    int M, int N, int K, int nbn)
{
  __shared__ unsigned short As[2][128 * 32];
  __shared__ unsigned short Bs[2][128 * 32];
  const int t = threadIdx.x;
  const int lane = t & 63;
  const int wave = t >> 6;
  const int wr = wave >> 1, wc = wave & 1;

  const int p = blockIdx.x;
  const int slot = p >> 3;
  const int g = slot / nbn;
  const int mi = (p & 7) + (g << 3);
  const int ni = slot - g * nbn;
  const long m0 = (long)mi * 128;
  const long n0 = (long)ni * 128;

  const int nsteps = K >> 5;
  const int r0 = lane & 15;
  const int kh = lane >> 4;

  f32x4 acc[4][4] = {};   // [nf][mf] (transposed D)

  const unsigned short* gA = A_F32 ? nullptr : (const unsigned short*)Ain + m0 * K;
  const float*          gA32 = A_F32 ? (const float*)Ain + m0 * K : nullptr;
  const unsigned short* gB = Bt + n0 * K;

  float4 areg[4];
  const int arow[1] = {0};  (void)arow;

  // --- staging helpers (compile-time unrolled, static indexing) ---
  #define LOAD_A32(s)                                                        \
    { _Pragma("unroll")                                                      \
      for (int j = 0; j < 4; ++j) {                                          \
        int idx = t + 256 * j;                                               \
        int row = idx >> 3, kq = (idx & 7) * 4;                              \
        areg[j] = *reinterpret_cast<const float4*>(gA32 + (size_t)row * K + (s) * 32 + kq); \
      } }
  #define WRITE_A(buf)                                                       \
    { _Pragma("unroll")                                                      \
      for (int j = 0; j < 4; ++j) {                                          \
        int idx = t + 256 * j;                                               \
        int row = idx >> 3, kq = (idx & 7) * 4;                              \
        u16x4 pw;                                                            \
        pw[0] = f2bf(areg[j].x); pw[1] = f2bf(areg[j].y);                    \
        pw[2] = f2bf(areg[j].z); pw[3] = f2bf(areg[j].w);                    \
        *reinterpret_cast<u16x4*>(&As[buf][row * 32 + kq]) = pw;             \
      } }
  #define GLOAD_A(s, buf)                                                    \
    { _Pragma("unroll")                                                      \
      for (int j = 0; j < 2; ++j) {                                          \
        int c = t + 256 * j;                                                 \
        int row = c >> 2, ko = (c & 3) << 3;                                 \
        gload16(gA + (size_t)row * K + (s) * 32 + ko, &As[buf][c * 8]);      \
      } }
  #define GLOAD_B(s, buf)                                                    \
    { _Pragma("unroll")                                                      \
      for (int j = 0; j < 2; ++j) {                                          \
        int c = t + 256 * j;                                                 \
        int row = c >> 2, ko = (c & 3) << 3;                                 \
        gload16(gB + (size_t)row * K + (s) * 32 + ko, &Bs[buf][c * 8]);      \
      } }

  // prologue: stage k-step 0 into buffer 0
  if (A_F32) { LOAD_A32(0); } else { GLOAD_A(0, 0); }
  GLOAD_B(0, 0);
  if (A_F32) { WRITE_A(0); }
  __syncthreads();

  for (int s = 0; s < nsteps; ++s) {
    int cur = s & 1;
    int nxt = cur ^ 1;
    if (s + 1 < nsteps) {
      if (A_F32) { LOAD_A32(s + 1); } else { GLOAD_A(s + 1, nxt); }
      GLOAD_B(s + 1, nxt);
    }
    bf16x8 af[4], bfr[4];
    #pragma unroll
    for (int mf = 0; mf < 4; ++mf)
      af[mf] = *reinterpret_cast<const bf16x8*>(&As[cur][(wr * 64 + mf * 16 + r0) * 32 + kh * 8]);
    #pragma unroll
    for (int nf = 0; nf < 4; ++nf)
      bfr[nf] = *reinterpret_cast<const bf16x8*>(&Bs[cur][(wc * 64 + nf * 16 + r0) * 32 + kh * 8]);
    #pragma unroll
    for (int nf = 0; nf < 4; ++nf) {
      #pragma unroll
      for (int mf = 0; mf < 4; ++mf)
        acc[nf][mf] = __builtin_amdgcn_mfma_f32_16x16x32_bf16(bfr[nf], af[mf], acc[nf][mf], 0, 0, 0);
    }
    if (A_F32 && s + 1 < nsteps) { WRITE_A(nxt); }
    __syncthreads();
  }

  // epilogue: transposed D -> lane holds 4 consecutive N-cols of one M-row
  #pragma unroll
  for (int nf = 0; nf < 4; ++nf) {
    long coln = n0 + wc * 64 + nf * 16 + kh * 4;
    f32x4 bv = *reinterpret_cast<const f32x4*>(&bias[coln]);
    #pragma unroll
    for (int mf = 0; mf < 4; ++mf) {
      long row = m0 + wr * 64 + mf * 16 + r0;
      f32x4 v = acc[nf][mf] + bv;
      if (OUT_BF16) {
        u16x4 pw;
        pw[0] = f2bf(v[0]); pw[1] = f2bf(v[1]);
        pw[2] = f2bf(v[2]); pw[3] = f2bf(v[3]);
        *reinterpret_cast<u16x4*>((unsigned short*)out + row * N + coln) = pw;
      } else {
        *reinterpret_cast<f32x4*>((float*)out + row * N + coln) = v;
      }
    }
  }
  #undef LOAD_A32
  #undef WRITE_A
  #undef GLOAD_A
  #undef GLOAD_B
}

// ---------------- shifted-window attention (S^T form, 8 waves = 8 heads) ----------------
__global__ __launch_bounds__(512, 4) void attn_kernel(
    const unsigned short* __restrict__ qkv,   // [NPIX][768] bf16
    const unsigned short* __restrict__ btab,  // [4][8][4096] bf16 bias+mask, D-frag order
    unsigned short* __restrict__ aout)        // [NPIX][256] bf16
{
  const int win = blockIdx.x;
  const int b = win >> 6;
  const int gi = (win >> 3) & 7;
  const int gj = win & 7;
  const int t = threadIdx.x;
  const int head = t >> 6;
  const int lane = t & 63;
  const int fr = lane & 15;     // fragment col lane part
  const int q = lane >> 4;      // lane quarter

  __shared__ unsigned short Vt[8][32 * 70];   // per head: Vt[d][j], stride 70; reused as out_s
  __shared__ int pix_s[64];

  if (t < 64) {
    int idx = (t < 49) ? t : 48;
    int wi = idx / 7, wj = idx - (idx / 7) * 7;
    int hs = gi * 7 + wi, ws = gj * 7 + wj;
    int ph = hs + 3; if (ph >= HWDIM) ph -= HWDIM;
    int pw = ws + 3; if (pw >= HWDIM) pw -= HWDIM;
    pix_s[t] = (b * HWDIM + ph) * HWDIM + pw;
  }
  __syncthreads();

  unsigned short* VtW = Vt[head];
  const int cls = (((gi == 7) ? 1 : 0) << 1) | ((gj == 7) ? 1 : 0);
  const unsigned short* bth = btab + (((cls << 3) | head) << 12);

  // ---- V -> LDS transposed (stride 70: conflict-free scatter) ----
  {
    int c = (lane & 3) * 8;
    #pragma unroll
    for (int it = 0; it < 4; ++it) {
      int j = (lane >> 2) + it * 16;
      u16x8 vv = {0, 0, 0, 0, 0, 0, 0, 0};
      if (j < 49)
        vv = *reinterpret_cast<const u16x8*>(
            qkv + (size_t)pix_s[j] * QKVN + 512 + head * 32 + c);
      #pragma unroll
      for (int e = 0; e < 8; ++e) VtW[(c + e) * 70 + j] = vv[e];
    }
  }

  // ---- Q/K fragments direct from global ----
  bf16x8 kf[4], qf[4];
  #pragma unroll
  for (int f = 0; f < 4; ++f) {
    int rj = f * 16 + fr;
    int p = pix_s[(rj < 49) ? rj : 48];
    const unsigned short* base = qkv + (size_t)p * QKVN + head * 32 + q * 8;
    qf[f] = *reinterpret_cast<const bf16x8*>(base);
    kf[f] = *reinterpret_cast<const bf16x8*>(base + 256);
  }

  // prefetch bias frags for jf=0 (hide L2 latency under MFMAs)
  u16x4 aw[2][4];
  #pragma unroll
  for (int c2 = 0; c2 < 4; ++c2)
    aw[0][c2] = *reinterpret_cast<const u16x4*>(bth + (c2 << 8) + (q << 6) + (fr << 2));

  // ---- S^T = K·Q^T ----
  f32x4 acc[4][4] = {};   // [jf][if]
  #pragma unroll
  for (int jf = 0; jf < 4; ++jf) {
    #pragma unroll
    for (int c2 = 0; c2 < 4; ++c2)
      acc[jf][c2] = __builtin_amdgcn_mfma_f32_16x16x32_bf16(kf[jf], qf[c2], acc[jf][c2], 0, 0, 0);
  }

  // ---- softmax over rows j: val = acc*scale + (bias+mask); exp; colsum ----
  const float scale = 0.17677669529663687f;  // 1/sqrt(32)
  float colsum[4] = {0.f, 0.f, 0.f, 0.f};
  unsigned pk[4][4][2];     // [jf][if][word]: bf16 pairs (r0|r1, r2|r3)
  #pragma unroll
  for (int jf = 0; jf < 4; ++jf) {
    if (jf < 3) {
      #pragma unroll
      for (int c2 = 0; c2 < 4; ++c2)
        aw[(jf + 1) & 1][c2] = *reinterpret_cast<const u16x4*>(
            bth + (((jf + 1) * 4 + c2) << 8) + (q << 6) + (fr << 2));
    }
    #pragma unroll
    for (int c2 = 0; c2 < 4; ++c2) {
      float ev[4];
      #pragma unroll
      for (int r = 0; r < 4; ++r) {
        float val = fmaf(acc[jf][c2][r], scale, bf2f(aw[jf & 1][c2][r]));
        ev[r] = __expf(val);
        colsum[c2] += ev[r];
      }
      unsigned h0 = f2bf(ev[0]), h1 = f2bf(ev[1]);
      unsigned h2 = f2bf(ev[2]), h3 = f2bf(ev[3]);
      pk[jf][c2][0] = h0 | (h1 << 16);
      pk[jf][c2][1] = h2 | (h3 << 16);
    }
  }
  float rinv[4];
  #pragma unroll
  for (int c2 = 0; c2 < 4; ++c2) {
    float s = colsum[c2];
    s += __shfl_xor(s, 16);
    s += __shfl_xor(s, 32);
    rinv[c2] = 1.0f / s;
  }

  // ---- PV: out^T[d][i] = sum_j Vt[d][j] * P^T[j][i], B-frag via lane remap ----
  const int srcA = ((q & 1) << 5) + fr;
  const int srcB = srcA + 16;
  const bool hi = (q >= 2);

  f32x4 outT[2][4] = {};   // [nt(d-block)][if]
  #pragma unroll
  for (int kb = 0; kb < 2; ++kb) {
    bf16x8 vfrag[2];
    #pragma unroll
    for (int nt = 0; nt < 2; ++nt)
      vfrag[nt] = *reinterpret_cast<const bf16x8*>(&VtW[(nt * 16 + fr) * 70 + kb * 32 + q * 8]);
    #pragma unroll
    for (int c2 = 0; c2 < 4; ++c2) {
      unsigned a0 = (unsigned)__shfl((int)pk[2 * kb][c2][0], srcA);
      unsigned a1 = (unsigned)__shfl((int)pk[2 * kb][c2][1], srcA);
      unsigned a2 = (unsigned)__shfl((int)pk[2 * kb][c2][0], srcB);
      unsigned a3 = (unsigned)__shfl((int)pk[2 * kb][c2][1], srcB);
      unsigned b0 = (unsigned)__shfl((int)pk[2 * kb + 1][c2][0], srcA);
      unsigned b1 = (unsigned)__shfl((int)pk[2 * kb + 1][c2][1], srcA);
      unsigned b2 = (unsigned)__shfl((int)pk[2 * kb + 1][c2][0], srcB);
      unsigned b3 = (unsigned)__shfl((int)pk[2 * kb + 1][c2][1], srcB);
      union { unsigned u[4]; bf16x8 v; } pf;
      pf.u[0] = hi ? b0 : a0;
      pf.u[1] = hi ? b1 : a1;
      pf.u[2] = hi ? b2 : a2;
      pf.u[3] = hi ? b3 : a3;
      #pragma unroll
      for (int nt = 0; nt < 2; ++nt)
        outT[nt][c2] = __builtin_amdgcn_mfma_f32_16x16x32_bf16(vfrag[nt], pf.v, outT[nt][c2], 0, 0, 0);
    }
  }

  // ---- stage output in LDS (reuse Vt), then coalesced global write ----
  unsigned short* out_s = Vt[0];
  __syncthreads();
  #pragma unroll
  for (int c2 = 0; c2 < 4; ++c2) {
    int i = c2 * 16 + fr;
    if (i < 49) {
      float rv = rinv[c2];
      unsigned m = (unsigned)((i & 7) << 4);
      #pragma unroll
      for (int nt = 0; nt < 2; ++nt) {
        f32x4 o = outT[nt][c2];
        u16x4 pkd;
        pkd[0] = f2bf(o[0] * rv); pkd[1] = f2bf(o[1] * rv);
        pkd[2] = f2bf(o[2] * rv); pkd[3] = f2bf(o[3] * rv);
        unsigned off = (unsigned)(i * 512 + head * 64 + nt * 32 + q * 8) ^ m;
        *reinterpret_cast<u16x4*>((char*)out_s + off) = pkd;
      }
    }
  }
  __syncthreads();
  for (int u = t; u < 1568; u += 512) {
    int row = u >> 5, seg = u & 31;
    unsigned off = (unsigned)(row * 512 + ((seg * 16) ^ ((row & 7) << 4)));
    u16x8 ch = *reinterpret_cast<const u16x8*>((const char*)out_s + off);
    *reinterpret_cast<u16x8*>((char*)(aout + (size_t)pix_s[row] * CDIM) + seg * 16) = ch;
  }
}

// ---------------- launch ----------------
extern "C" void kernel_launch(void* const* d_in, const int* in_sizes, int n_in,
                              void* d_out, int out_size, void* d_ws, size_t ws_size,
                              hipStream_t stream) {
  const float* x      = (const float*)d_in[0];
  const float* qkv_w  = (const float*)d_in[1];
  const float* qkv_b  = (const float*)d_in[2];
  const float* proj_w = (const float*)d_in[3];
  const float* proj_b = (const float*)d_in[4];
  const float* table  = (const float*)d_in[5];

  char* ws = (char*)d_ws;
  unsigned short* aout    = (unsigned short*)ws;                 // 51 MB region
  unsigned short* qkv_bf  = (unsigned short*)(ws + 51380224);
  unsigned short* qkvw_bf = (unsigned short*)(ws + 205520896);
  unsigned short* projw_bf= (unsigned short*)(ws + 205914112);
  unsigned short* btab    = (unsigned short*)(ws + 206045184);  // 256 KB

  cvt_kernel<<<96, 256, 0, stream>>>(qkv_w, qkvw_bf, QKVN * CDIM / 8);
  cvt_kernel<<<32, 256, 0, stream>>>(proj_w, projw_bf, CDIM * CDIM / 8);
  bias_pre<<<512, 256, 0, stream>>>(table, btab);

  // QKV GEMM with fused fp32->bf16 convert of x
  gemm_kernel<true, true><<<784 * 6, 256, 0, stream>>>(x, qkvw_bf, qkv_b, qkv_bf,
                                                       NPIX, QKVN, CDIM, 6);

  attn_kernel<<<2048, 512, 0, stream>>>(qkv_bf, btab, aout);

  gemm_kernel<false, false><<<784 * 2, 256, 0, stream>>>(aout, projw_bf, proj_b, (float*)d_out,
                                                         NPIX, CDIM, CDIM, 2);
}

// Round 8
// 215.430 us; speedup vs baseline: 1.0486x; 1.0486x over previous
//
#include <hip/hip_runtime.h>
#include <stdint.h>

typedef __attribute__((ext_vector_type(4))) float f32x4;
typedef __attribute__((ext_vector_type(8))) short bf16x8;
typedef __attribute__((ext_vector_type(8))) unsigned short u16x8;
typedef __attribute__((ext_vector_type(4))) unsigned short u16x4;

#define NPIX 100352      // 32*56*56
#define CDIM 256
#define QKVN 768
#define HWDIM 56

__device__ __forceinline__ unsigned short f2bf(float f) {
  union { float f; unsigned int u; } cv; cv.f = f;
  unsigned int u = cv.u;
  unsigned int r = (u + 0x7FFFu + ((u >> 16) & 1u)) >> 16;
  return (unsigned short)r;
}
__device__ __forceinline__ float bf2f(unsigned short h) {
  union { unsigned int u; float f; } cv; cv.u = ((unsigned int)h) << 16;
  return cv.f;
}

// ---------------- fp32 -> bf16 convert (8 elems/thread) ----------------
__global__ __launch_bounds__(256) void cvt_kernel(const float* __restrict__ in,
                                                  unsigned short* __restrict__ out,
                                                  int n8) {
  int i = blockIdx.x * 256 + threadIdx.x;
  if (i >= n8) return;
  const float4* p = reinterpret_cast<const float4*>(in) + (size_t)i * 2;
  float4 a = p[0], b = p[1];
  u16x8 r;
  r[0] = f2bf(a.x); r[1] = f2bf(a.y); r[2] = f2bf(a.z); r[3] = f2bf(a.w);
  r[4] = f2bf(b.x); r[5] = f2bf(b.y); r[6] = f2bf(b.z); r[7] = f2bf(b.w);
  *(reinterpret_cast<u16x8*>(out) + i) = r;
}

// ---------------- bias+mask table precompute ----------------
// layout: [cls][head][jf][c2][q][fr][r] bf16 -> lane (q,fr) loads u16x4 per (jf,c2)
__global__ __launch_bounds__(256) void bias_pre(const float* __restrict__ table,
                                                unsigned short* __restrict__ bt) {
  int e = blockIdx.x * 256 + threadIdx.x;       // 131072 total
  int r  = e & 3;
  int fr = (e >> 2) & 15;
  int q  = (e >> 6) & 3;
  int c2 = (e >> 8) & 3;
  int jf = (e >> 10) & 3;
  int h  = (e >> 12) & 7;
  int cls = (e >> 15) & 3;
  int j = jf * 16 + q * 4 + r;
  int i = c2 * 16 + fr;
  float v;
  if (j > 48 || i > 48) {
    v = -1e30f;
  } else {
    int bh = cls >> 1, bw = cls & 1;
    int iwi = i / 7, iwj = i % 7;
    int jwi = j / 7, jwj = j % 7;
    int ireg = (bh ? ((iwi < 4) ? 1 : 2) : 0) * 3 + (bw ? ((iwj < 4) ? 1 : 2) : 0);
    int jreg = (bh ? ((jwi < 4) ? 1 : 2) : 0) * 3 + (bw ? ((jwj < 4) ? 1 : 2) : 0);
    float m = (ireg == jreg) ? 0.f : -100.f;
    v = table[((iwi - jwi + 6) * 13 + (iwj - jwj + 6)) * 8 + h] + m;
  }
  bt[e] = f2bf(v);
}

// ---------------- proj GEMM: C[M,N] = A[M,K] * Bt[N,K]^T + bias (fp32 out) ----------------
__device__ __forceinline__ void gload16(const unsigned short* g, unsigned short* l) {
  __builtin_amdgcn_global_load_lds((const __attribute__((address_space(1))) void*)g,
                                   (__attribute__((address_space(3))) void*)l, 16, 0, 0);
}

__global__ __launch_bounds__(256) void gemm_proj(
    const unsigned short* __restrict__ A,
    const unsigned short* __restrict__ Bt,
    const float* __restrict__ bias,
    float* __restrict__ out,
    int M, int N, int K, int nbn)
{
  __shared__ unsigned short As[2][128 * 32];
  __shared__ unsigned short Bs[2][128 * 32];
  const int t = threadIdx.x;
  const int lane = t & 63;
  const int wave = t >> 6;
  const int wr = wave >> 1, wc = wave & 1;

  const int p = blockIdx.x;
  const int slot = p >> 3;
  const int g = slot / nbn;
  const int mi = (p & 7) + (g << 3);
  const int ni = slot - g * nbn;
  const long m0 = (long)mi * 128;
  const long n0 = (long)ni * 128;

  const int nsteps = K >> 5;
  const int r0 = lane & 15;
  const int kh = lane >> 4;

  f32x4 acc[4][4] = {};   // [nf][mf] transposed D

  const unsigned short* gA = A + m0 * K;
  const unsigned short* gB = Bt + n0 * K;

  {
    #pragma unroll
    for (int j = 0; j < 2; ++j) {
      int c = t + 256 * j;
      int row = c >> 2, ko = (c & 3) << 3;
      gload16(gA + (size_t)row * K + ko, &As[0][c * 8]);
      gload16(gB + (size_t)row * K + ko, &Bs[0][c * 8]);
    }
  }
  __syncthreads();

  for (int s = 0; s < nsteps; ++s) {
    int cur = s & 1;
    if (s + 1 < nsteps) {
      const unsigned short* gA2 = gA + (s + 1) * 32;
      const unsigned short* gB2 = gB + (s + 1) * 32;
      #pragma unroll
      for (int j = 0; j < 2; ++j) {
        int c = t + 256 * j;
        int row = c >> 2, ko = (c & 3) << 3;
        gload16(gA2 + (size_t)row * K + ko, &As[cur ^ 1][c * 8]);
        gload16(gB2 + (size_t)row * K + ko, &Bs[cur ^ 1][c * 8]);
      }
    }
    bf16x8 af[4], bfr[4];
    #pragma unroll
    for (int mf = 0; mf < 4; ++mf)
      af[mf] = *reinterpret_cast<const bf16x8*>(&As[cur][(wr * 64 + mf * 16 + r0) * 32 + kh * 8]);
    #pragma unroll
    for (int nf = 0; nf < 4; ++nf)
      bfr[nf] = *reinterpret_cast<const bf16x8*>(&Bs[cur][(wc * 64 + nf * 16 + r0) * 32 + kh * 8]);
    #pragma unroll
    for (int nf = 0; nf < 4; ++nf) {
      #pragma unroll
      for (int mf = 0; mf < 4; ++mf)
        acc[nf][mf] = __builtin_amdgcn_mfma_f32_16x16x32_bf16(bfr[nf], af[mf], acc[nf][mf], 0, 0, 0);
    }
    __syncthreads();
  }

  #pragma unroll
  for (int nf = 0; nf < 4; ++nf) {
    long coln = n0 + wc * 64 + nf * 16 + kh * 4;
    f32x4 bv = *reinterpret_cast<const f32x4*>(&bias[coln]);
    #pragma unroll
    for (int mf = 0; mf < 4; ++mf) {
      long row = m0 + wr * 64 + mf * 16 + r0;
      *reinterpret_cast<f32x4*>(out + row * N + coln) = acc[nf][mf] + bv;
    }
  }
}

// ---------------- fused QKV-GEMM + shifted-window attention ----------------
// block = window (512 threads, 8 waves = 8 heads)
__global__ __launch_bounds__(512, 4) void fused_attn(
    const float* __restrict__ x,              // [NPIX][256] fp32, pixel order
    const unsigned short* __restrict__ wqkv,  // [768][256] bf16
    const float* __restrict__ bqkv,           // [768]
    const unsigned short* __restrict__ btab,  // [4][8][4096] bf16
    unsigned short* __restrict__ aout)        // [NPIX][256] bf16
{
  const int win = blockIdx.x;
  const int b = win >> 6;
  const int gi = (win >> 3) & 7;
  const int gj = win & 7;
  const int t = threadIdx.x;
  const int head = t >> 6;
  const int lane = t & 63;
  const int fr = lane & 15;
  const int q = lane >> 4;

  __shared__ unsigned short x_s[49 * 264];    // x window bf16, stride 264; reused as out_s
  __shared__ unsigned short Vt[8][32 * 70];   // per head Vt[d][j], stride 70
  __shared__ int pix_s[64];

  if (t < 64) {
    int idx = (t < 49) ? t : 48;
    int wi = idx / 7, wj = idx - (idx / 7) * 7;
    int hs = gi * 7 + wi, ws2 = gj * 7 + wj;
    int ph = hs + 3; if (ph >= HWDIM) ph -= HWDIM;
    int pw = ws2 + 3; if (pw >= HWDIM) pw -= HWDIM;
    pix_s[t] = (b * HWDIM + ph) * HWDIM + pw;
  }
  __syncthreads();

  // ---- stage x window -> LDS bf16 (49 x 256) ----
  for (int u = t; u < 49 * 32; u += 512) {
    int pix = u >> 5, seg = u & 31;
    const float4* src = reinterpret_cast<const float4*>(x + (size_t)pix_s[pix] * CDIM + seg * 8);
    float4 a = src[0], c = src[1];
    u16x8 r;
    r[0] = f2bf(a.x); r[1] = f2bf(a.y); r[2] = f2bf(a.z); r[3] = f2bf(a.w);
    r[4] = f2bf(c.x); r[5] = f2bf(c.y); r[6] = f2bf(c.z); r[7] = f2bf(c.w);
    *reinterpret_cast<u16x8*>(&x_s[pix * 264 + seg * 8]) = r;
  }
  __syncthreads();

  const int cls = (((gi == 7) ? 1 : 0) << 1) | ((gj == 7) ? 1 : 0);
  const unsigned short* bth = btab + (((cls << 3) | head) << 12);
  unsigned short* VtW = Vt[head];
  const int srcA = ((q & 1) << 5) + fr;
  const int srcB = srcA + 16;
  const bool hi = (q >= 2);

  f32x4 acc[2][4];

  // one QKV sub-matrix: D[dim][pix]; lane holds dim=(l>>4)*4+r of pix=l&15
  #define COMPUTE_MAT(mo)                                                              \
  { _Pragma("unroll") for (int d = 0; d < 2; ++d)                                      \
      { acc[d][0] = (f32x4){0.f,0.f,0.f,0.f}; acc[d][1] = acc[d][0];                   \
        acc[d][2] = acc[d][0]; acc[d][3] = acc[d][0]; }                                \
    _Pragma("unroll") for (int ks = 0; ks < 8; ++ks) {                                 \
      bf16x8 wf0 = *reinterpret_cast<const bf16x8*>(wqkv + (size_t)((mo) + head * 32 + fr) * 256 + ks * 32 + q * 8);       \
      bf16x8 wf1 = *reinterpret_cast<const bf16x8*>(wqkv + (size_t)((mo) + head * 32 + 16 + fr) * 256 + ks * 32 + q * 8);  \
      bf16x8 xf0 = *reinterpret_cast<const bf16x8*>(&x_s[(fr)      * 264 + ks * 32 + q * 8]);  \
      bf16x8 xf1 = *reinterpret_cast<const bf16x8*>(&x_s[(16 + fr) * 264 + ks * 32 + q * 8]);  \
      bf16x8 xf2 = *reinterpret_cast<const bf16x8*>(&x_s[(32 + fr) * 264 + ks * 32 + q * 8]);  \
      bf16x8 x3r = *reinterpret_cast<const bf16x8*>(&x_s[48 * 264 + ks * 32 + q * 8]);         \
      bf16x8 xf3 = (fr == 0) ? x3r : (bf16x8){0,0,0,0,0,0,0,0};                        \
      acc[0][0] = __builtin_amdgcn_mfma_f32_16x16x32_bf16(wf0, xf0, acc[0][0], 0,0,0); \
      acc[0][1] = __builtin_amdgcn_mfma_f32_16x16x32_bf16(wf0, xf1, acc[0][1], 0,0,0); \
      acc[0][2] = __builtin_amdgcn_mfma_f32_16x16x32_bf16(wf0, xf2, acc[0][2], 0,0,0); \
      acc[0][3] = __builtin_amdgcn_mfma_f32_16x16x32_bf16(wf0, xf3, acc[0][3], 0,0,0); \
      acc[1][0] = __builtin_amdgcn_mfma_f32_16x16x32_bf16(wf1, xf0, acc[1][0], 0,0,0); \
      acc[1][1] = __builtin_amdgcn_mfma_f32_16x16x32_bf16(wf1, xf1, acc[1][1], 0,0,0); \
      acc[1][2] = __builtin_amdgcn_mfma_f32_16x16x32_bf16(wf1, xf2, acc[1][2], 0,0,0); \
      acc[1][3] = __builtin_amdgcn_mfma_f32_16x16x32_bf16(wf1, xf3, acc[1][3], 0,0,0); \
    }                                                                                  \
    _Pragma("unroll") for (int d = 0; d < 2; ++d) {                                    \
      f32x4 bv = *reinterpret_cast<const f32x4*>(bqkv + (mo) + head * 32 + d * 16 + q * 4); \
      acc[d][0] += bv; acc[d][1] += bv; acc[d][2] += bv; acc[d][3] += bv;              \
    } }

  #define PACK_MAT(pkm)                                                                \
  { _Pragma("unroll") for (int d = 0; d < 2; ++d)                                      \
      _Pragma("unroll") for (int p2 = 0; p2 < 4; ++p2) {                               \
        pkm[d][p2][0] = (unsigned)f2bf(acc[d][p2][0]) | ((unsigned)f2bf(acc[d][p2][1]) << 16); \
        pkm[d][p2][1] = (unsigned)f2bf(acc[d][p2][2]) | ((unsigned)f2bf(acc[d][p2][3]) << 16); \
      } }

  // remap D-form packed words -> MFMA input frag ([pix][dim], k=(l>>4)*8+e)
  #define BUILD_FRAG(pkm, p2, dst)                                                     \
  { unsigned a0 = (unsigned)__shfl((int)pkm[0][p2][0], srcA);                          \
    unsigned a1 = (unsigned)__shfl((int)pkm[0][p2][1], srcA);                          \
    unsigned a2 = (unsigned)__shfl((int)pkm[0][p2][0], srcB);                          \
    unsigned a3 = (unsigned)__shfl((int)pkm[0][p2][1], srcB);                          \
    unsigned b0 = (unsigned)__shfl((int)pkm[1][p2][0], srcA);                          \
    unsigned b1 = (unsigned)__shfl((int)pkm[1][p2][1], srcA);                          \
    unsigned b2 = (unsigned)__shfl((int)pkm[1][p2][0], srcB);                          \
    unsigned b3 = (unsigned)__shfl((int)pkm[1][p2][1], srcB);                          \
    union { unsigned u[4]; bf16x8 v; } uf;                                             \
    uf.u[0] = hi ? b0 : a0; uf.u[1] = hi ? b1 : a1;                                    \
    uf.u[2] = hi ? b2 : a2; uf.u[3] = hi ? b3 : a3;                                    \
    dst = uf.v; }

  unsigned pkk[2][4][2], pkq[2][4][2];
  COMPUTE_MAT(256); PACK_MAT(pkk);   // K
  COMPUTE_MAT(0);   PACK_MAT(pkq);   // Q

  bf16x8 qf[4];
  BUILD_FRAG(pkq, 0, qf[0]); BUILD_FRAG(pkq, 1, qf[1]);
  BUILD_FRAG(pkq, 2, qf[2]); BUILD_FRAG(pkq, 3, qf[3]);

  // ---- S^T + softmax (identical math to verified round-6 path) ----
  const float scale = 0.17677669529663687f;  // 1/sqrt(32)
  u16x4 aw[2][4];
  #pragma unroll
  for (int c2 = 0; c2 < 4; ++c2)
    aw[0][c2] = *reinterpret_cast<const u16x4*>(bth + (c2 << 8) + (q << 6) + (fr << 2));
  float colsum[4] = {0.f, 0.f, 0.f, 0.f};
  unsigned pk[4][4][2];
  #pragma unroll
  for (int jf = 0; jf < 4; ++jf) {
    bf16x8 kfj;
    BUILD_FRAG(pkk, jf, kfj);
    f32x4 sacc[4];
    #pragma unroll
    for (int c2 = 0; c2 < 4; ++c2) {
      f32x4 z = {0.f, 0.f, 0.f, 0.f};
      sacc[c2] = __builtin_amdgcn_mfma_f32_16x16x32_bf16(kfj, qf[c2], z, 0, 0, 0);
    }
    if (jf < 3) {
      #pragma unroll
      for (int c2 = 0; c2 < 4; ++c2)
        aw[(jf + 1) & 1][c2] = *reinterpret_cast<const u16x4*>(
            bth + (((jf + 1) * 4 + c2) << 8) + (q << 6) + (fr << 2));
    }
    #pragma unroll
    for (int c2 = 0; c2 < 4; ++c2) {
      float ev[4];
      #pragma unroll
      for (int r = 0; r < 4; ++r) {
        float val = fmaf(sacc[c2][r], scale, bf2f(aw[jf & 1][c2][r]));
        ev[r] = __expf(val);
        colsum[c2] += ev[r];
      }
      unsigned h0 = f2bf(ev[0]), h1 = f2bf(ev[1]);
      unsigned h2 = f2bf(ev[2]), h3 = f2bf(ev[3]);
      pk[jf][c2][0] = h0 | (h1 << 16);
      pk[jf][c2][1] = h2 | (h3 << 16);
    }
  }
  float rinv[4];
  #pragma unroll
  for (int c2 = 0; c2 < 4; ++c2) {
    float s = colsum[c2];
    s += __shfl_xor(s, 16);
    s += __shfl_xor(s, 32);
    rinv[c2] = 1.0f / s;
  }

  // ---- V ----
  COMPUTE_MAT(512);
  #pragma unroll
  for (int d = 0; d < 2; ++d)
    #pragma unroll
    for (int p2 = 0; p2 < 4; ++p2)
      #pragma unroll
      for (int r = 0; r < 4; ++r)
        VtW[(d * 16 + q * 4 + r) * 70 + p2 * 16 + fr] = f2bf(acc[d][p2][r]);

  // ---- PV: out^T[d][i] = sum_j Vt[d][j] * P^T[j][i] ----
  f32x4 outT[2][4] = {};
  #pragma unroll
  for (int kb = 0; kb < 2; ++kb) {
    bf16x8 vf0 = *reinterpret_cast<const bf16x8*>(&VtW[(fr)      * 70 + kb * 32 + q * 8]);
    bf16x8 vf1 = *reinterpret_cast<const bf16x8*>(&VtW[(16 + fr) * 70 + kb * 32 + q * 8]);
    #pragma unroll
    for (int c2 = 0; c2 < 4; ++c2) {
      unsigned a0 = (unsigned)__shfl((int)pk[2 * kb][c2][0], srcA);
      unsigned a1 = (unsigned)__shfl((int)pk[2 * kb][c2][1], srcA);
      unsigned a2 = (unsigned)__shfl((int)pk[2 * kb][c2][0], srcB);
      unsigned a3 = (unsigned)__shfl((int)pk[2 * kb][c2][1], srcB);
      unsigned b0 = (unsigned)__shfl((int)pk[2 * kb + 1][c2][0], srcA);
      unsigned b1 = (unsigned)__shfl((int)pk[2 * kb + 1][c2][1], srcA);
      unsigned b2 = (unsigned)__shfl((int)pk[2 * kb + 1][c2][0], srcB);
      unsigned b3 = (unsigned)__shfl((int)pk[2 * kb + 1][c2][1], srcB);
      union { unsigned u[4]; bf16x8 v; } pf;
      pf.u[0] = hi ? b0 : a0;
      pf.u[1] = hi ? b1 : a1;
      pf.u[2] = hi ? b2 : a2;
      pf.u[3] = hi ? b3 : a3;
      outT[0][c2] = __builtin_amdgcn_mfma_f32_16x16x32_bf16(vf0, pf.v, outT[0][c2], 0, 0, 0);
      outT[1][c2] = __builtin_amdgcn_mfma_f32_16x16x32_bf16(vf1, pf.v, outT[1][c2], 0, 0, 0);
    }
  }

  // ---- stage output in LDS (reuse x_s), coalesced global write ----
  unsigned short* out_s = x_s;
  __syncthreads();   // all waves done reading x_s / own Vt
  #pragma unroll
  for (int c2 = 0; c2 < 4; ++c2) {
    int i = c2 * 16 + fr;
    if (i < 49) {
      float rv = rinv[c2];
      unsigned m = (unsigned)((i & 7) << 4);
      #pragma unroll
      for (int nt = 0; nt < 2; ++nt) {
        f32x4 o = outT[nt][c2];
        u16x4 pkd;
        pkd[0] = f2bf(o[0] * rv); pkd[1] = f2bf(o[1] * rv);
        pkd[2] = f2bf(o[2] * rv); pkd[3] = f2bf(o[3] * rv);
        unsigned off = (unsigned)(i * 512 + head * 64 + nt * 32 + q * 8) ^ m;
        *reinterpret_cast<u16x4*>((char*)out_s + off) = pkd;
      }
    }
  }
  __syncthreads();
  for (int u = t; u < 1568; u += 512) {
    int row = u >> 5, seg = u & 31;
    unsigned off = (unsigned)(row * 512 + ((seg * 16) ^ ((row & 7) << 4)));
    u16x8 ch = *reinterpret_cast<const u16x8*>((const char*)out_s + off);
    *reinterpret_cast<u16x8*>((char*)(aout + (size_t)pix_s[row] * CDIM) + seg * 16) = ch;
  }
  #undef COMPUTE_MAT
  #undef PACK_MAT
  #undef BUILD_FRAG
}

// ---------------- launch ----------------
extern "C" void kernel_launch(void* const* d_in, const int* in_sizes, int n_in,
                              void* d_out, int out_size, void* d_ws, size_t ws_size,
                              hipStream_t stream) {
  const float* x      = (const float*)d_in[0];
  const float* qkv_w  = (const float*)d_in[1];
  const float* qkv_b  = (const float*)d_in[2];
  const float* proj_w = (const float*)d_in[3];
  const float* proj_b = (const float*)d_in[4];
  const float* table  = (const float*)d_in[5];

  char* ws = (char*)d_ws;
  unsigned short* aout    = (unsigned short*)ws;                 // 51,380,224 B
  unsigned short* qkvw_bf = (unsigned short*)(ws + 51380224);    // 393,216 B
  unsigned short* projw_bf= (unsigned short*)(ws + 51773440);    // 131,072 B
  unsigned short* btab    = (unsigned short*)(ws + 51904512);    // 262,144 B

  cvt_kernel<<<96, 256, 0, stream>>>(qkv_w, qkvw_bf, QKVN * CDIM / 8);
  cvt_kernel<<<32, 256, 0, stream>>>(proj_w, projw_bf, CDIM * CDIM / 8);
  bias_pre<<<512, 256, 0, stream>>>(table, btab);

  fused_attn<<<2048, 512, 0, stream>>>(x, qkvw_bf, qkv_b, btab, aout);

  gemm_proj<<<784 * 2, 256, 0, stream>>>(aout, projw_bf, proj_b, (float*)d_out,
                                         NPIX, CDIM, CDIM, 2);
}

// Round 9
// 200.187 us; speedup vs baseline: 1.1284x; 1.0761x over previous
//
#include <hip/hip_runtime.h>
#include <stdint.h>

typedef __attribute__((ext_vector_type(4))) float f32x4;
typedef __attribute__((ext_vector_type(8))) short bf16x8;
typedef __attribute__((ext_vector_type(8))) unsigned short u16x8;
typedef __attribute__((ext_vector_type(4))) unsigned short u16x4;

#define NPIX 100352      // 32*56*56
#define CDIM 256
#define QKVN 768
#define HWDIM 56

__device__ __forceinline__ unsigned short f2bf(float f) {
  union { float f; unsigned int u; } cv; cv.f = f;
  unsigned int u = cv.u;
  unsigned int r = (u + 0x7FFFu + ((u >> 16) & 1u)) >> 16;
  return (unsigned short)r;
}
__device__ __forceinline__ float bf2f(unsigned short h) {
  union { unsigned int u; float f; } cv; cv.u = ((unsigned int)h) << 16;
  return cv.f;
}

// ---------------- fp32 -> bf16 convert (8 elems/thread) ----------------
__global__ __launch_bounds__(256) void cvt_kernel(const float* __restrict__ in,
                                                  unsigned short* __restrict__ out,
                                                  int n8) {
  int i = blockIdx.x * 256 + threadIdx.x;
  if (i >= n8) return;
  const float4* p = reinterpret_cast<const float4*>(in) + (size_t)i * 2;
  float4 a = p[0], b = p[1];
  u16x8 r;
  r[0] = f2bf(a.x); r[1] = f2bf(a.y); r[2] = f2bf(a.z); r[3] = f2bf(a.w);
  r[4] = f2bf(b.x); r[5] = f2bf(b.y); r[6] = f2bf(b.z); r[7] = f2bf(b.w);
  *(reinterpret_cast<u16x8*>(out) + i) = r;
}

// ---------------- bias+mask table precompute ----------------
// layout: [cls][head][jf][c2][q][fr][r] bf16 -> lane (q,fr) loads u16x4 per (jf,c2)
__global__ __launch_bounds__(256) void bias_pre(const float* __restrict__ table,
                                                unsigned short* __restrict__ bt) {
  int e = blockIdx.x * 256 + threadIdx.x;       // 131072 total
  int r  = e & 3;
  int fr = (e >> 2) & 15;
  int q  = (e >> 6) & 3;
  int c2 = (e >> 8) & 3;
  int jf = (e >> 10) & 3;
  int h  = (e >> 12) & 7;
  int cls = (e >> 15) & 3;
  int j = jf * 16 + q * 4 + r;
  int i = c2 * 16 + fr;
  float v;
  if (j > 48 || i > 48) {
    v = -1e30f;
  } else {
    int bh = cls >> 1, bw = cls & 1;
    int iwi = i / 7, iwj = i % 7;
    int jwi = j / 7, jwj = j % 7;
    int ireg = (bh ? ((iwi < 4) ? 1 : 2) : 0) * 3 + (bw ? ((iwj < 4) ? 1 : 2) : 0);
    int jreg = (bh ? ((jwi < 4) ? 1 : 2) : 0) * 3 + (bw ? ((jwj < 4) ? 1 : 2) : 0);
    float m = (ireg == jreg) ? 0.f : -100.f;
    v = table[((iwi - jwi + 6) * 13 + (iwj - jwj + 6)) * 8 + h] + m;
  }
  bt[e] = f2bf(v);
}

// ---------------- proj GEMM: C[M,N] = A[M,K] * Bt[N,K]^T + bias (fp32 out) ----------------
__device__ __forceinline__ void gload16(const unsigned short* g, unsigned short* l) {
  __builtin_amdgcn_global_load_lds((const __attribute__((address_space(1))) void*)g,
                                   (__attribute__((address_space(3))) void*)l, 16, 0, 0);
}

__global__ __launch_bounds__(256) void gemm_proj(
    const unsigned short* __restrict__ A,
    const unsigned short* __restrict__ Bt,
    const float* __restrict__ bias,
    float* __restrict__ out,
    int M, int N, int K, int nbn)
{
  __shared__ unsigned short As[2][128 * 32];
  __shared__ unsigned short Bs[2][128 * 32];
  const int t = threadIdx.x;
  const int lane = t & 63;
  const int wave = t >> 6;
  const int wr = wave >> 1, wc = wave & 1;

  const int p = blockIdx.x;
  const int slot = p >> 3;
  const int g = slot / nbn;
  const int mi = (p & 7) + (g << 3);
  const int ni = slot - g * nbn;
  const long m0 = (long)mi * 128;
  const long n0 = (long)ni * 128;

  const int nsteps = K >> 5;
  const int r0 = lane & 15;
  const int kh = lane >> 4;

  f32x4 acc[4][4] = {};   // [nf][mf] transposed D

  const unsigned short* gA = A + m0 * K;
  const unsigned short* gB = Bt + n0 * K;

  {
    #pragma unroll
    for (int j = 0; j < 2; ++j) {
      int c = t + 256 * j;
      int row = c >> 2, ko = (c & 3) << 3;
      gload16(gA + (size_t)row * K + ko, &As[0][c * 8]);
      gload16(gB + (size_t)row * K + ko, &Bs[0][c * 8]);
    }
  }
  __syncthreads();

  for (int s = 0; s < nsteps; ++s) {
    int cur = s & 1;
    if (s + 1 < nsteps) {
      const unsigned short* gA2 = gA + (s + 1) * 32;
      const unsigned short* gB2 = gB + (s + 1) * 32;
      #pragma unroll
      for (int j = 0; j < 2; ++j) {
        int c = t + 256 * j;
        int row = c >> 2, ko = (c & 3) << 3;
        gload16(gA2 + (size_t)row * K + ko, &As[cur ^ 1][c * 8]);
        gload16(gB2 + (size_t)row * K + ko, &Bs[cur ^ 1][c * 8]);
      }
    }
    bf16x8 af[4], bfr[4];
    #pragma unroll
    for (int mf = 0; mf < 4; ++mf)
      af[mf] = *reinterpret_cast<const bf16x8*>(&As[cur][(wr * 64 + mf * 16 + r0) * 32 + kh * 8]);
    #pragma unroll
    for (int nf = 0; nf < 4; ++nf)
      bfr[nf] = *reinterpret_cast<const bf16x8*>(&Bs[cur][(wc * 64 + nf * 16 + r0) * 32 + kh * 8]);
    #pragma unroll
    for (int nf = 0; nf < 4; ++nf) {
      #pragma unroll
      for (int mf = 0; mf < 4; ++mf)
        acc[nf][mf] = __builtin_amdgcn_mfma_f32_16x16x32_bf16(bfr[nf], af[mf], acc[nf][mf], 0, 0, 0);
    }
    __syncthreads();
  }

  #pragma unroll
  for (int nf = 0; nf < 4; ++nf) {
    long coln = n0 + wc * 64 + nf * 16 + kh * 4;
    f32x4 bv = *reinterpret_cast<const f32x4*>(&bias[coln]);
    #pragma unroll
    for (int mf = 0; mf < 4; ++mf) {
      long row = m0 + wr * 64 + mf * 16 + r0;
      *reinterpret_cast<f32x4*>(out + row * N + coln) = acc[nf][mf] + bv;
    }
  }
}

// ---------------- fused QKV-GEMM + shifted-window attention ----------------
// block = window (512 threads, 8 waves = 8 heads); 2 blocks/CU (LDS-limited)
__global__ __launch_bounds__(512, 2) void fused_attn(
    const float* __restrict__ x,              // [NPIX][256] fp32, pixel order
    const unsigned short* __restrict__ wqkv,  // [768][256] bf16
    const float* __restrict__ bqkv,           // [768]
    const unsigned short* __restrict__ btab,  // [4][8][4096] bf16
    unsigned short* __restrict__ aout)        // [NPIX][256] bf16
{
  const int win = blockIdx.x;
  const int b = win >> 6;
  const int gi = (win >> 3) & 7;
  const int gj = win & 7;
  const int t = threadIdx.x;
  const int head = t >> 6;
  const int lane = t & 63;
  const int fr = lane & 15;
  const int q = lane >> 4;

  __shared__ unsigned short x_s[49 * 256];    // x window bf16, XOR-swizzled rows; reused as out_s
  __shared__ unsigned short Vt[8][32 * 70];   // per head Vt[d][j], stride 70
  __shared__ int pix_s[64];

  if (t < 64) {
    int idx = (t < 49) ? t : 48;
    int wi = idx / 7, wj = idx - (idx / 7) * 7;
    int hs = gi * 7 + wi, ws2 = gj * 7 + wj;
    int ph = hs + 3; if (ph >= HWDIM) ph -= HWDIM;
    int pw = ws2 + 3; if (pw >= HWDIM) pw -= HWDIM;
    pix_s[t] = (b * HWDIM + ph) * HWDIM + pw;
  }
  __syncthreads();

  // byte offset into x_s for (row, bytecol): XOR swizzle -> 2-way banks max
  #define XS(row, bc) ((unsigned)((row) * 512 + (((bc)) ^ (((row) & 7) << 4))))

  // ---- stage x window -> LDS bf16 (49 x 256, swizzled) ----
  for (int u = t; u < 49 * 32; u += 512) {
    int pix = u >> 5, seg = u & 31;
    const float4* src = reinterpret_cast<const float4*>(x + (size_t)pix_s[pix] * CDIM + seg * 8);
    float4 a = src[0], c = src[1];
    u16x8 r;
    r[0] = f2bf(a.x); r[1] = f2bf(a.y); r[2] = f2bf(a.z); r[3] = f2bf(a.w);
    r[4] = f2bf(c.x); r[5] = f2bf(c.y); r[6] = f2bf(c.z); r[7] = f2bf(c.w);
    *reinterpret_cast<u16x8*>((char*)x_s + XS(pix, seg * 16)) = r;
  }
  __syncthreads();

  const int cls = (((gi == 7) ? 1 : 0) << 1) | ((gj == 7) ? 1 : 0);
  const unsigned short* bth = btab + (((cls << 3) | head) << 12);
  unsigned short* VtW = Vt[head];
  const int srcA = ((q & 1) << 5) + fr;
  const int srcB = srcA + 16;
  const bool hi = (q >= 2);

  f32x4 acc[2][4];

  // one QKV sub-matrix: D[dim][pix]; lane holds dim=(l>>4)*4+r of pix=l&15
  #define COMPUTE_MAT(mo)                                                              \
  { _Pragma("unroll") for (int d = 0; d < 2; ++d)                                      \
      { acc[d][0] = (f32x4){0.f,0.f,0.f,0.f}; acc[d][1] = acc[d][0];                   \
        acc[d][2] = acc[d][0]; acc[d][3] = acc[d][0]; }                                \
    _Pragma("unroll") for (int ks = 0; ks < 8; ++ks) {                                 \
      bf16x8 wf0 = *reinterpret_cast<const bf16x8*>(wqkv + (size_t)((mo) + head * 32 + fr) * 256 + ks * 32 + q * 8);       \
      bf16x8 wf1 = *reinterpret_cast<const bf16x8*>(wqkv + (size_t)((mo) + head * 32 + 16 + fr) * 256 + ks * 32 + q * 8);  \
      int bc = ks * 64 + q * 16;                                                       \
      bf16x8 xf0 = *reinterpret_cast<const bf16x8*>((const char*)x_s + XS(fr, bc));    \
      bf16x8 xf1 = *reinterpret_cast<const bf16x8*>((const char*)x_s + XS(16 + fr, bc)); \
      bf16x8 xf2 = *reinterpret_cast<const bf16x8*>((const char*)x_s + XS(32 + fr, bc)); \
      bf16x8 x3r = *reinterpret_cast<const bf16x8*>((const char*)x_s + XS(48, bc));    \
      bf16x8 xf3 = (fr == 0) ? x3r : (bf16x8){0,0,0,0,0,0,0,0};                        \
      acc[0][0] = __builtin_amdgcn_mfma_f32_16x16x32_bf16(wf0, xf0, acc[0][0], 0,0,0); \
      acc[0][1] = __builtin_amdgcn_mfma_f32_16x16x32_bf16(wf0, xf1, acc[0][1], 0,0,0); \
      acc[0][2] = __builtin_amdgcn_mfma_f32_16x16x32_bf16(wf0, xf2, acc[0][2], 0,0,0); \
      acc[0][3] = __builtin_amdgcn_mfma_f32_16x16x32_bf16(wf0, xf3, acc[0][3], 0,0,0); \
      acc[1][0] = __builtin_amdgcn_mfma_f32_16x16x32_bf16(wf1, xf0, acc[1][0], 0,0,0); \
      acc[1][1] = __builtin_amdgcn_mfma_f32_16x16x32_bf16(wf1, xf1, acc[1][1], 0,0,0); \
      acc[1][2] = __builtin_amdgcn_mfma_f32_16x16x32_bf16(wf1, xf2, acc[1][2], 0,0,0); \
      acc[1][3] = __builtin_amdgcn_mfma_f32_16x16x32_bf16(wf1, xf3, acc[1][3], 0,0,0); \
    }                                                                                  \
    _Pragma("unroll") for (int d = 0; d < 2; ++d) {                                    \
      f32x4 bv = *reinterpret_cast<const f32x4*>(bqkv + (mo) + head * 32 + d * 16 + q * 4); \
      acc[d][0] += bv; acc[d][1] += bv; acc[d][2] += bv; acc[d][3] += bv;              \
    } }

  #define PACK_MAT(pkm)                                                                \
  { _Pragma("unroll") for (int d = 0; d < 2; ++d)                                      \
      _Pragma("unroll") for (int p2 = 0; p2 < 4; ++p2) {                               \
        pkm[d][p2][0] = (unsigned)f2bf(acc[d][p2][0]) | ((unsigned)f2bf(acc[d][p2][1]) << 16); \
        pkm[d][p2][1] = (unsigned)f2bf(acc[d][p2][2]) | ((unsigned)f2bf(acc[d][p2][3]) << 16); \
      } }

  // remap D-form packed words -> MFMA input frag ([pix][dim], k=(l>>4)*8+e)
  #define BUILD_FRAG(pkm, p2, dst)                                                     \
  { unsigned a0 = (unsigned)__shfl((int)pkm[0][p2][0], srcA);                          \
    unsigned a1 = (unsigned)__shfl((int)pkm[0][p2][1], srcA);                          \
    unsigned a2 = (unsigned)__shfl((int)pkm[0][p2][0], srcB);                          \
    unsigned a3 = (unsigned)__shfl((int)pkm[0][p2][1], srcB);                          \
    unsigned b0 = (unsigned)__shfl((int)pkm[1][p2][0], srcA);                          \
    unsigned b1 = (unsigned)__shfl((int)pkm[1][p2][1], srcA);                          \
    unsigned b2 = (unsigned)__shfl((int)pkm[1][p2][0], srcB);                          \
    unsigned b3 = (unsigned)__shfl((int)pkm[1][p2][1], srcB);                          \
    union { unsigned u[4]; bf16x8 v; } uf;                                             \
    uf.u[0] = hi ? b0 : a0; uf.u[1] = hi ? b1 : a1;                                    \
    uf.u[2] = hi ? b2 : a2; uf.u[3] = hi ? b3 : a3;                                    \
    dst = uf.v; }

  // ---- V first (acc released before the register-heavy phase) ----
  COMPUTE_MAT(512);
  #pragma unroll
  for (int d = 0; d < 2; ++d)
    #pragma unroll
    for (int p2 = 0; p2 < 4; ++p2)
      #pragma unroll
      for (int r = 0; r < 4; ++r)
        VtW[(d * 16 + q * 4 + r) * 70 + p2 * 16 + fr] = f2bf(acc[d][p2][r]);

  // ---- K, then Q (pkq dies immediately after qf built) ----
  unsigned pkk[2][4][2];
  COMPUTE_MAT(256); PACK_MAT(pkk);
  bf16x8 qf[4];
  {
    unsigned pkq[2][4][2];
    COMPUTE_MAT(0); PACK_MAT(pkq);
    BUILD_FRAG(pkq, 0, qf[0]); BUILD_FRAG(pkq, 1, qf[1]);
    BUILD_FRAG(pkq, 2, qf[2]); BUILD_FRAG(pkq, 3, qf[3]);
  }

  // ---- S^T + softmax ----
  const float scale = 0.17677669529663687f;  // 1/sqrt(32)
  u16x4 aw[2][4];
  #pragma unroll
  for (int c2 = 0; c2 < 4; ++c2)
    aw[0][c2] = *reinterpret_cast<const u16x4*>(bth + (c2 << 8) + (q << 6) + (fr << 2));
  float colsum[4] = {0.f, 0.f, 0.f, 0.f};
  unsigned pk[4][4][2];
  #pragma unroll
  for (int jf = 0; jf < 4; ++jf) {
    bf16x8 kfj;
    BUILD_FRAG(pkk, jf, kfj);
    f32x4 sacc[4];
    #pragma unroll
    for (int c2 = 0; c2 < 4; ++c2) {
      f32x4 z = {0.f, 0.f, 0.f, 0.f};
      sacc[c2] = __builtin_amdgcn_mfma_f32_16x16x32_bf16(kfj, qf[c2], z, 0, 0, 0);
    }
    if (jf < 3) {
      #pragma unroll
      for (int c2 = 0; c2 < 4; ++c2)
        aw[(jf + 1) & 1][c2] = *reinterpret_cast<const u16x4*>(
            bth + (((jf + 1) * 4 + c2) << 8) + (q << 6) + (fr << 2));
    }
    #pragma unroll
    for (int c2 = 0; c2 < 4; ++c2) {
      float ev[4];
      #pragma unroll
      for (int r = 0; r < 4; ++r) {
        float val = fmaf(sacc[c2][r], scale, bf2f(aw[jf & 1][c2][r]));
        ev[r] = __expf(val);
        colsum[c2] += ev[r];
      }
      unsigned h0 = f2bf(ev[0]), h1 = f2bf(ev[1]);
      unsigned h2 = f2bf(ev[2]), h3 = f2bf(ev[3]);
      pk[jf][c2][0] = h0 | (h1 << 16);
      pk[jf][c2][1] = h2 | (h3 << 16);
    }
  }
  float rinv[4];
  #pragma unroll
  for (int c2 = 0; c2 < 4; ++c2) {
    float s = colsum[c2];
    s += __shfl_xor(s, 16);
    s += __shfl_xor(s, 32);
    rinv[c2] = 1.0f / s;
  }

  // ---- PV: out^T[d][i] = sum_j Vt[d][j] * P^T[j][i] ----
  f32x4 outT[2][4] = {};
  #pragma unroll
  for (int kb = 0; kb < 2; ++kb) {
    bf16x8 vf0 = *reinterpret_cast<const bf16x8*>(&VtW[(fr)      * 70 + kb * 32 + q * 8]);
    bf16x8 vf1 = *reinterpret_cast<const bf16x8*>(&VtW[(16 + fr) * 70 + kb * 32 + q * 8]);
    #pragma unroll
    for (int c2 = 0; c2 < 4; ++c2) {
      unsigned a0 = (unsigned)__shfl((int)pk[2 * kb][c2][0], srcA);
      unsigned a1 = (unsigned)__shfl((int)pk[2 * kb][c2][1], srcA);
      unsigned a2 = (unsigned)__shfl((int)pk[2 * kb][c2][0], srcB);
      unsigned a3 = (unsigned)__shfl((int)pk[2 * kb][c2][1], srcB);
      unsigned b0 = (unsigned)__shfl((int)pk[2 * kb + 1][c2][0], srcA);
      unsigned b1 = (unsigned)__shfl((int)pk[2 * kb + 1][c2][1], srcA);
      unsigned b2 = (unsigned)__shfl((int)pk[2 * kb + 1][c2][0], srcB);
      unsigned b3 = (unsigned)__shfl((int)pk[2 * kb + 1][c2][1], srcB);
      union { unsigned u[4]; bf16x8 v; } pf;
      pf.u[0] = hi ? b0 : a0;
      pf.u[1] = hi ? b1 : a1;
      pf.u[2] = hi ? b2 : a2;
      pf.u[3] = hi ? b3 : a3;
      outT[0][c2] = __builtin_amdgcn_mfma_f32_16x16x32_bf16(vf0, pf.v, outT[0][c2], 0, 0, 0);
      outT[1][c2] = __builtin_amdgcn_mfma_f32_16x16x32_bf16(vf1, pf.v, outT[1][c2], 0, 0, 0);
    }
  }

  // ---- stage output in LDS (reuse x_s), coalesced global write ----
  unsigned short* out_s = x_s;
  __syncthreads();   // all waves done reading x_s / own Vt
  #pragma unroll
  for (int c2 = 0; c2 < 4; ++c2) {
    int i = c2 * 16 + fr;
    if (i < 49) {
      float rv = rinv[c2];
      #pragma unroll
      for (int nt = 0; nt < 2; ++nt) {
        f32x4 o = outT[nt][c2];
        u16x4 pkd;
        pkd[0] = f2bf(o[0] * rv); pkd[1] = f2bf(o[1] * rv);
        pkd[2] = f2bf(o[2] * rv); pkd[3] = f2bf(o[3] * rv);
        *reinterpret_cast<u16x4*>((char*)out_s + XS(i, head * 64 + nt * 32 + q * 8)) = pkd;
      }
    }
  }
  __syncthreads();
  for (int u = t; u < 1568; u += 512) {
    int row = u >> 5, seg = u & 31;
    u16x8 ch = *reinterpret_cast<const u16x8*>((const char*)out_s + XS(row, seg * 16));
    *reinterpret_cast<u16x8*>((char*)(aout + (size_t)pix_s[row] * CDIM) + seg * 16) = ch;
  }
  #undef COMPUTE_MAT
  #undef PACK_MAT
  #undef BUILD_FRAG
  #undef XS
}

// ---------------- launch ----------------
extern "C" void kernel_launch(void* const* d_in, const int* in_sizes, int n_in,
                              void* d_out, int out_size, void* d_ws, size_t ws_size,
                              hipStream_t stream) {
  const float* x      = (const float*)d_in[0];
  const float* qkv_w  = (const float*)d_in[1];
  const float* qkv_b  = (const float*)d_in[2];
  const float* proj_w = (const float*)d_in[3];
  const float* proj_b = (const float*)d_in[4];
  const float* table  = (const float*)d_in[5];

  char* ws = (char*)d_ws;
  unsigned short* aout    = (unsigned short*)ws;                 // 51,380,224 B
  unsigned short* qkvw_bf = (unsigned short*)(ws + 51380224);    // 393,216 B
  unsigned short* projw_bf= (unsigned short*)(ws + 51773440);    // 131,072 B
  unsigned short* btab    = (unsigned short*)(ws + 51904512);    // 262,144 B

  cvt_kernel<<<96, 256, 0, stream>>>(qkv_w, qkvw_bf, QKVN * CDIM / 8);
  cvt_kernel<<<32, 256, 0, stream>>>(proj_w, projw_bf, CDIM * CDIM / 8);
  bias_pre<<<512, 256, 0, stream>>>(table, btab);

  fused_attn<<<2048, 512, 0, stream>>>(x, qkvw_bf, qkv_b, btab, aout);

  gemm_proj<<<784 * 2, 256, 0, stream>>>(aout, projw_bf, proj_b, (float*)d_out,
                                         NPIX, CDIM, CDIM, 2);
}

// Round 10
// 163.691 us; speedup vs baseline: 1.3800x; 1.2230x over previous
//
#include <hip/hip_runtime.h>
#include <stdint.h>

typedef __attribute__((ext_vector_type(4))) float f32x4;
typedef __attribute__((ext_vector_type(8))) short bf16x8;
typedef __attribute__((ext_vector_type(8))) unsigned short u16x8;
typedef __attribute__((ext_vector_type(4))) unsigned short u16x4;

#define NPIX 100352      // 32*56*56
#define CDIM 256
#define QKVN 768
#define HWDIM 56

__device__ __forceinline__ unsigned short f2bf(float f) {
  union { float f; unsigned int u; } cv; cv.f = f;
  unsigned int u = cv.u;
  unsigned int r = (u + 0x7FFFu + ((u >> 16) & 1u)) >> 16;
  return (unsigned short)r;
}
__device__ __forceinline__ float bf2f(unsigned short h) {
  union { unsigned int u; float f; } cv; cv.u = ((unsigned int)h) << 16;
  return cv.f;
}

// ---------------- fp32 -> bf16 convert (8 elems/thread) ----------------
__global__ __launch_bounds__(256) void cvt_kernel(const float* __restrict__ in,
                                                  unsigned short* __restrict__ out,
                                                  int n8) {
  int i = blockIdx.x * 256 + threadIdx.x;
  if (i >= n8) return;
  const float4* p = reinterpret_cast<const float4*>(in) + (size_t)i * 2;
  float4 a = p[0], b = p[1];
  u16x8 r;
  r[0] = f2bf(a.x); r[1] = f2bf(a.y); r[2] = f2bf(a.z); r[3] = f2bf(a.w);
  r[4] = f2bf(b.x); r[5] = f2bf(b.y); r[6] = f2bf(b.z); r[7] = f2bf(b.w);
  *(reinterpret_cast<u16x8*>(out) + i) = r;
}

// ---------------- Wqkv -> fragment-ordered bf16 table ----------------
// wtab element base for (mat,h,ks,wsel,lane) = ((((mat*8+h)*8+ks)*2+wsel)*64+lane)*8
// holding W[mat*256 + h*32 + wsel*16 + (lane&15)][ks*32 + (lane>>4)*8 .. +8]
__global__ __launch_bounds__(256) void wqkv_pre(const float* __restrict__ w,
                                                unsigned short* __restrict__ wtab) {
  int e8 = blockIdx.x * 256 + threadIdx.x;   // 24576 total
  int l = e8 & 63;
  int t1 = e8 >> 6;
  int wsel = t1 & 1;
  int ks = (t1 >> 1) & 7;
  int h = (t1 >> 4) & 7;
  int m = t1 >> 7;          // 0..2
  int row = m * 256 + h * 32 + wsel * 16 + (l & 15);
  int col = ks * 32 + (l >> 4) * 8;
  const float4* src = reinterpret_cast<const float4*>(w + (size_t)row * 256 + col);
  float4 a = src[0], b = src[1];
  u16x8 r;
  r[0] = f2bf(a.x); r[1] = f2bf(a.y); r[2] = f2bf(a.z); r[3] = f2bf(a.w);
  r[4] = f2bf(b.x); r[5] = f2bf(b.y); r[6] = f2bf(b.z); r[7] = f2bf(b.w);
  *reinterpret_cast<u16x8*>(wtab + (size_t)e8 * 8) = r;
}

// ---------------- bias+mask table precompute ----------------
__global__ __launch_bounds__(256) void bias_pre(const float* __restrict__ table,
                                                unsigned short* __restrict__ bt) {
  int e = blockIdx.x * 256 + threadIdx.x;       // 131072 total
  int r  = e & 3;
  int fr = (e >> 2) & 15;
  int q  = (e >> 6) & 3;
  int c2 = (e >> 8) & 3;
  int jf = (e >> 10) & 3;
  int h  = (e >> 12) & 7;
  int cls = (e >> 15) & 3;
  int j = jf * 16 + q * 4 + r;
  int i = c2 * 16 + fr;
  float v;
  if (j > 48 || i > 48) {
    v = -1e30f;
  } else {
    int bh = cls >> 1, bw = cls & 1;
    int iwi = i / 7, iwj = i % 7;
    int jwi = j / 7, jwj = j % 7;
    int ireg = (bh ? ((iwi < 4) ? 1 : 2) : 0) * 3 + (bw ? ((iwj < 4) ? 1 : 2) : 0);
    int jreg = (bh ? ((jwi < 4) ? 1 : 2) : 0) * 3 + (bw ? ((jwj < 4) ? 1 : 2) : 0);
    float m = (ireg == jreg) ? 0.f : -100.f;
    v = table[((iwi - jwi + 6) * 13 + (iwj - jwj + 6)) * 8 + h] + m;
  }
  bt[e] = f2bf(v);
}

// ---------------- proj GEMM: C[M,N] = A[M,K] * Bt[N,K]^T + bias (fp32 out) ----------------
__device__ __forceinline__ void gload16(const unsigned short* g, unsigned short* l) {
  __builtin_amdgcn_global_load_lds((const __attribute__((address_space(1))) void*)g,
                                   (__attribute__((address_space(3))) void*)l, 16, 0, 0);
}

__global__ __launch_bounds__(256) void gemm_proj(
    const unsigned short* __restrict__ A,
    const unsigned short* __restrict__ Bt,
    const float* __restrict__ bias,
    float* __restrict__ out,
    int M, int N, int K, int nbn)
{
  __shared__ unsigned short As[2][128 * 32];
  __shared__ unsigned short Bs[2][128 * 32];
  const int t = threadIdx.x;
  const int lane = t & 63;
  const int wave = t >> 6;
  const int wr = wave >> 1, wc = wave & 1;

  const int p = blockIdx.x;
  const int slot = p >> 3;
  const int g = slot / nbn;
  const int mi = (p & 7) + (g << 3);
  const int ni = slot - g * nbn;
  const long m0 = (long)mi * 128;
  const long n0 = (long)ni * 128;

  const int nsteps = K >> 5;
  const int r0 = lane & 15;
  const int kh = lane >> 4;

  f32x4 acc[4][4] = {};   // [nf][mf] transposed D

  const unsigned short* gA = A + m0 * K;
  const unsigned short* gB = Bt + n0 * K;

  {
    #pragma unroll
    for (int j = 0; j < 2; ++j) {
      int c = t + 256 * j;
      int row = c >> 2, ko = (c & 3) << 3;
      gload16(gA + (size_t)row * K + ko, &As[0][c * 8]);
      gload16(gB + (size_t)row * K + ko, &Bs[0][c * 8]);
    }
  }
  __syncthreads();

  for (int s = 0; s < nsteps; ++s) {
    int cur = s & 1;
    if (s + 1 < nsteps) {
      const unsigned short* gA2 = gA + (s + 1) * 32;
      const unsigned short* gB2 = gB + (s + 1) * 32;
      #pragma unroll
      for (int j = 0; j < 2; ++j) {
        int c = t + 256 * j;
        int row = c >> 2, ko = (c & 3) << 3;
        gload16(gA2 + (size_t)row * K + ko, &As[cur ^ 1][c * 8]);
        gload16(gB2 + (size_t)row * K + ko, &Bs[cur ^ 1][c * 8]);
      }
    }
    bf16x8 af[4], bfr[4];
    #pragma unroll
    for (int mf = 0; mf < 4; ++mf)
      af[mf] = *reinterpret_cast<const bf16x8*>(&As[cur][(wr * 64 + mf * 16 + r0) * 32 + kh * 8]);
    #pragma unroll
    for (int nf = 0; nf < 4; ++nf)
      bfr[nf] = *reinterpret_cast<const bf16x8*>(&Bs[cur][(wc * 64 + nf * 16 + r0) * 32 + kh * 8]);
    #pragma unroll
    for (int nf = 0; nf < 4; ++nf) {
      #pragma unroll
      for (int mf = 0; mf < 4; ++mf)
        acc[nf][mf] = __builtin_amdgcn_mfma_f32_16x16x32_bf16(bfr[nf], af[mf], acc[nf][mf], 0, 0, 0);
    }
    __syncthreads();
  }

  #pragma unroll
  for (int nf = 0; nf < 4; ++nf) {
    long coln = n0 + wc * 64 + nf * 16 + kh * 4;
    f32x4 bv = *reinterpret_cast<const f32x4*>(&bias[coln]);
    #pragma unroll
    for (int mf = 0; mf < 4; ++mf) {
      long row = m0 + wr * 64 + mf * 16 + r0;
      *reinterpret_cast<f32x4*>(out + row * N + coln) = acc[nf][mf] + bv;
    }
  }
}

// ---------------- fused QKV-GEMM + shifted-window attention ----------------
// block = window (512 threads, 8 waves = 8 heads); 2 blocks/CU (LDS-limited)
__global__ __launch_bounds__(512, 2) void fused_attn(
    const float* __restrict__ x,              // [NPIX][256] fp32, pixel order
    const unsigned short* __restrict__ wtab,  // fragment-ordered Wqkv bf16
    const float* __restrict__ bqkv,           // [768]
    const unsigned short* __restrict__ btab,  // [4][8][4096] bf16
    unsigned short* __restrict__ aout)        // [NPIX][256] bf16
{
  const int win = blockIdx.x;
  const int b = win >> 6;
  const int gi = (win >> 3) & 7;
  const int gj = win & 7;
  const int t = threadIdx.x;
  const int head = t >> 6;
  const int lane = t & 63;
  const int fr = lane & 15;
  const int q = lane >> 4;

  __shared__ unsigned short x_s[49 * 256];    // x window bf16, XOR-swizzled rows; reused as out_s
  __shared__ unsigned short Vt[8][32 * 70];   // per head Vt[d][j], stride 70
  __shared__ int pix_s[64];

  if (t < 64) {
    int idx = (t < 49) ? t : 48;
    int wi = idx / 7, wj = idx - (idx / 7) * 7;
    int hs = gi * 7 + wi, ws2 = gj * 7 + wj;
    int ph = hs + 3; if (ph >= HWDIM) ph -= HWDIM;
    int pw = ws2 + 3; if (pw >= HWDIM) pw -= HWDIM;
    pix_s[t] = (b * HWDIM + ph) * HWDIM + pw;
  }
  __syncthreads();

  // byte offset into x_s for (row, bytecol): XOR swizzle -> 2-way banks max
  #define XS(row, bc) ((unsigned)((row) * 512 + (((bc)) ^ (((row) & 7) << 4))))

  // ---- stage x window -> LDS bf16 (49 x 256, swizzled) ----
  for (int u = t; u < 49 * 32; u += 512) {
    int pix = u >> 5, seg = u & 31;
    const float4* src = reinterpret_cast<const float4*>(x + (size_t)pix_s[pix] * CDIM + seg * 8);
    float4 a = src[0], c = src[1];
    u16x8 r;
    r[0] = f2bf(a.x); r[1] = f2bf(a.y); r[2] = f2bf(a.z); r[3] = f2bf(a.w);
    r[4] = f2bf(c.x); r[5] = f2bf(c.y); r[6] = f2bf(c.z); r[7] = f2bf(c.w);
    *reinterpret_cast<u16x8*>((char*)x_s + XS(pix, seg * 16)) = r;
  }
  __syncthreads();

  const int cls = (((gi == 7) ? 1 : 0) << 1) | ((gj == 7) ? 1 : 0);
  const unsigned short* bth = btab + (((cls << 3) | head) << 12);
  unsigned short* VtW = Vt[head];
  const int srcA = ((q & 1) << 5) + fr;
  const int srcB = srcA + 16;
  const bool hi = (q >= 2);

  #define PACK_MAT(pkm)                                                                \
  { _Pragma("unroll") for (int d = 0; d < 2; ++d)                                      \
      _Pragma("unroll") for (int p2 = 0; p2 < 4; ++p2) {                               \
        pkm[d][p2][0] = (unsigned)f2bf(acc[d][p2][0]) | ((unsigned)f2bf(acc[d][p2][1]) << 16); \
        pkm[d][p2][1] = (unsigned)f2bf(acc[d][p2][2]) | ((unsigned)f2bf(acc[d][p2][3]) << 16); \
      } }

  #define BUILD_FRAG(pkm, p2, dst)                                                     \
  { unsigned a0 = (unsigned)__shfl((int)pkm[0][p2][0], srcA);                          \
    unsigned a1 = (unsigned)__shfl((int)pkm[0][p2][1], srcA);                          \
    unsigned a2 = (unsigned)__shfl((int)pkm[0][p2][0], srcB);                          \
    unsigned a3 = (unsigned)__shfl((int)pkm[0][p2][1], srcB);                          \
    unsigned b0 = (unsigned)__shfl((int)pkm[1][p2][0], srcA);                          \
    unsigned b1 = (unsigned)__shfl((int)pkm[1][p2][1], srcA);                          \
    unsigned b2 = (unsigned)__shfl((int)pkm[1][p2][0], srcB);                          \
    unsigned b3 = (unsigned)__shfl((int)pkm[1][p2][1], srcB);                          \
    union { unsigned u[4]; bf16x8 v; } uf;                                             \
    uf.u[0] = hi ? b0 : a0; uf.u[1] = hi ? b1 : a1;                                    \
    uf.u[2] = hi ? b2 : a2; uf.u[3] = hi ? b3 : a3;                                    \
    dst = uf.v; }

  // ---- QKV via one shared loop body: mat 2=V, 1=K, 0=Q ----
  unsigned pkk[2][4][2], pkq[2][4][2];
  {
    f32x4 acc[2][4];
    #pragma unroll 1
    for (int m = 0; m < 3; ++m) {
      const int mat = 2 - m;
      #pragma unroll
      for (int d = 0; d < 2; ++d)
        #pragma unroll
        for (int p2 = 0; p2 < 4; ++p2)
          acc[d][p2] = (f32x4){0.f, 0.f, 0.f, 0.f};
      #pragma unroll
      for (int ks = 0; ks < 8; ++ks) {
        const unsigned short* wb = wtab + (size_t)((((mat * 8 + head) * 8 + ks) * 128 + lane) * 8);
        bf16x8 wf0 = *reinterpret_cast<const bf16x8*>(wb);
        bf16x8 wf1 = *reinterpret_cast<const bf16x8*>(wb + 512);
        int bc = ks * 64 + q * 16;
        bf16x8 xf0 = *reinterpret_cast<const bf16x8*>((const char*)x_s + XS(fr, bc));
        bf16x8 xf1 = *reinterpret_cast<const bf16x8*>((const char*)x_s + XS(16 + fr, bc));
        bf16x8 xf2 = *reinterpret_cast<const bf16x8*>((const char*)x_s + XS(32 + fr, bc));
        bf16x8 x3r = *reinterpret_cast<const bf16x8*>((const char*)x_s + XS(48, bc));
        bf16x8 xf3 = (fr == 0) ? x3r : (bf16x8){0, 0, 0, 0, 0, 0, 0, 0};
        acc[0][0] = __builtin_amdgcn_mfma_f32_16x16x32_bf16(wf0, xf0, acc[0][0], 0, 0, 0);
        acc[0][1] = __builtin_amdgcn_mfma_f32_16x16x32_bf16(wf0, xf1, acc[0][1], 0, 0, 0);
        acc[0][2] = __builtin_amdgcn_mfma_f32_16x16x32_bf16(wf0, xf2, acc[0][2], 0, 0, 0);
        acc[0][3] = __builtin_amdgcn_mfma_f32_16x16x32_bf16(wf0, xf3, acc[0][3], 0, 0, 0);
        acc[1][0] = __builtin_amdgcn_mfma_f32_16x16x32_bf16(wf1, xf0, acc[1][0], 0, 0, 0);
        acc[1][1] = __builtin_amdgcn_mfma_f32_16x16x32_bf16(wf1, xf1, acc[1][1], 0, 0, 0);
        acc[1][2] = __builtin_amdgcn_mfma_f32_16x16x32_bf16(wf1, xf2, acc[1][2], 0, 0, 0);
        acc[1][3] = __builtin_amdgcn_mfma_f32_16x16x32_bf16(wf1, xf3, acc[1][3], 0, 0, 0);
      }
      #pragma unroll
      for (int d = 0; d < 2; ++d) {
        f32x4 bv = *reinterpret_cast<const f32x4*>(bqkv + mat * 256 + head * 32 + d * 16 + q * 4);
        acc[d][0] += bv; acc[d][1] += bv; acc[d][2] += bv; acc[d][3] += bv;
      }
      if (mat == 2) {
        #pragma unroll
        for (int d = 0; d < 2; ++d)
          #pragma unroll
          for (int p2 = 0; p2 < 4; ++p2)
            #pragma unroll
            for (int r = 0; r < 4; ++r)
              VtW[(d * 16 + q * 4 + r) * 70 + p2 * 16 + fr] = f2bf(acc[d][p2][r]);
      } else if (mat == 1) {
        PACK_MAT(pkk);
      } else {
        PACK_MAT(pkq);
      }
    }
  }

  bf16x8 qf[4];
  BUILD_FRAG(pkq, 0, qf[0]); BUILD_FRAG(pkq, 1, qf[1]);
  BUILD_FRAG(pkq, 2, qf[2]); BUILD_FRAG(pkq, 3, qf[3]);

  // ---- S^T + softmax ----
  const float scale = 0.17677669529663687f;  // 1/sqrt(32)
  u16x4 aw[2][4];
  #pragma unroll
  for (int c2 = 0; c2 < 4; ++c2)
    aw[0][c2] = *reinterpret_cast<const u16x4*>(bth + (c2 << 8) + (q << 6) + (fr << 2));
  float colsum[4] = {0.f, 0.f, 0.f, 0.f};
  unsigned pk[4][4][2];
  #pragma unroll
  for (int jf = 0; jf < 4; ++jf) {
    bf16x8 kfj;
    BUILD_FRAG(pkk, jf, kfj);
    f32x4 sacc[4];
    #pragma unroll
    for (int c2 = 0; c2 < 4; ++c2) {
      f32x4 z = {0.f, 0.f, 0.f, 0.f};
      sacc[c2] = __builtin_amdgcn_mfma_f32_16x16x32_bf16(kfj, qf[c2], z, 0, 0, 0);
    }
    if (jf < 3) {
      #pragma unroll
      for (int c2 = 0; c2 < 4; ++c2)
        aw[(jf + 1) & 1][c2] = *reinterpret_cast<const u16x4*>(
            bth + (((jf + 1) * 4 + c2) << 8) + (q << 6) + (fr << 2));
    }
    #pragma unroll
    for (int c2 = 0; c2 < 4; ++c2) {
      float ev[4];
      #pragma unroll
      for (int r = 0; r < 4; ++r) {
        float val = fmaf(sacc[c2][r], scale, bf2f(aw[jf & 1][c2][r]));
        ev[r] = __expf(val);
        colsum[c2] += ev[r];
      }
      unsigned h0 = f2bf(ev[0]), h1 = f2bf(ev[1]);
      unsigned h2 = f2bf(ev[2]), h3 = f2bf(ev[3]);
      pk[jf][c2][0] = h0 | (h1 << 16);
      pk[jf][c2][1] = h2 | (h3 << 16);
    }
  }
  float rinv[4];
  #pragma unroll
  for (int c2 = 0; c2 < 4; ++c2) {
    float s = colsum[c2];
    s += __shfl_xor(s, 16);
    s += __shfl_xor(s, 32);
    rinv[c2] = 1.0f / s;
  }

  // ---- PV: out^T[d][i] = sum_j Vt[d][j] * P^T[j][i] ----
  f32x4 outT[2][4] = {};
  #pragma unroll
  for (int kb = 0; kb < 2; ++kb) {
    bf16x8 vf0 = *reinterpret_cast<const bf16x8*>(&VtW[(fr)      * 70 + kb * 32 + q * 8]);
    bf16x8 vf1 = *reinterpret_cast<const bf16x8*>(&VtW[(16 + fr) * 70 + kb * 32 + q * 8]);
    #pragma unroll
    for (int c2 = 0; c2 < 4; ++c2) {
      bf16x8 pf;
      BUILD_FRAG_PV: ;
      {
        unsigned a0 = (unsigned)__shfl((int)pk[2 * kb][c2][0], srcA);
        unsigned a1 = (unsigned)__shfl((int)pk[2 * kb][c2][1], srcA);
        unsigned a2 = (unsigned)__shfl((int)pk[2 * kb][c2][0], srcB);
        unsigned a3 = (unsigned)__shfl((int)pk[2 * kb][c2][1], srcB);
        unsigned b0 = (unsigned)__shfl((int)pk[2 * kb + 1][c2][0], srcA);
        unsigned b1 = (unsigned)__shfl((int)pk[2 * kb + 1][c2][1], srcA);
        unsigned b2 = (unsigned)__shfl((int)pk[2 * kb + 1][c2][0], srcB);
        unsigned b3 = (unsigned)__shfl((int)pk[2 * kb + 1][c2][1], srcB);
        union { unsigned u[4]; bf16x8 v; } pfv;
        pfv.u[0] = hi ? b0 : a0;
        pfv.u[1] = hi ? b1 : a1;
        pfv.u[2] = hi ? b2 : a2;
        pfv.u[3] = hi ? b3 : a3;
        pf = pfv.v;
      }
      outT[0][c2] = __builtin_amdgcn_mfma_f32_16x16x32_bf16(vf0, pf, outT[0][c2], 0, 0, 0);
      outT[1][c2] = __builtin_amdgcn_mfma_f32_16x16x32_bf16(vf1, pf, outT[1][c2], 0, 0, 0);
    }
  }

  // ---- stage output in LDS (reuse x_s), coalesced global write ----
  unsigned short* out_s = x_s;
  __syncthreads();   // all waves done reading x_s / own Vt
  #pragma unroll
  for (int c2 = 0; c2 < 4; ++c2) {
    int i = c2 * 16 + fr;
    if (i < 49) {
      float rv = rinv[c2];
      #pragma unroll
      for (int nt = 0; nt < 2; ++nt) {
        f32x4 o = outT[nt][c2];
        u16x4 pkd;
        pkd[0] = f2bf(o[0] * rv); pkd[1] = f2bf(o[1] * rv);
        pkd[2] = f2bf(o[2] * rv); pkd[3] = f2bf(o[3] * rv);
        *reinterpret_cast<u16x4*>((char*)out_s + XS(i, head * 64 + nt * 32 + q * 8)) = pkd;
      }
    }
  }
  __syncthreads();
  for (int u = t; u < 1568; u += 512) {
    int row = u >> 5, seg = u & 31;
    u16x8 ch = *reinterpret_cast<const u16x8*>((const char*)out_s + XS(row, seg * 16));
    *reinterpret_cast<u16x8*>((char*)(aout + (size_t)pix_s[row] * CDIM) + seg * 16) = ch;
  }
  #undef PACK_MAT
  #undef BUILD_FRAG
  #undef XS
}

// ---------------- launch ----------------
extern "C" void kernel_launch(void* const* d_in, const int* in_sizes, int n_in,
                              void* d_out, int out_size, void* d_ws, size_t ws_size,
                              hipStream_t stream) {
  const float* x      = (const float*)d_in[0];
  const float* qkv_w  = (const float*)d_in[1];
  const float* qkv_b  = (const float*)d_in[2];
  const float* proj_w = (const float*)d_in[3];
  const float* proj_b = (const float*)d_in[4];
  const float* table  = (const float*)d_in[5];

  char* ws = (char*)d_ws;
  unsigned short* aout    = (unsigned short*)ws;                 // 51,380,224 B
  unsigned short* projw_bf= (unsigned short*)(ws + 51380224);    // 131,072 B
  unsigned short* btab    = (unsigned short*)(ws + 51511296);    // 262,144 B
  unsigned short* wtab    = (unsigned short*)(ws + 51773440);    // 393,216 B

  cvt_kernel<<<32, 256, 0, stream>>>(proj_w, projw_bf, CDIM * CDIM / 8);
  bias_pre<<<512, 256, 0, stream>>>(table, btab);
  wqkv_pre<<<96, 256, 0, stream>>>(qkv_w, wtab);

  fused_attn<<<2048, 512, 0, stream>>>(x, wtab, qkv_b, btab, aout);

  gemm_proj<<<784 * 2, 256, 0, stream>>>(aout, projw_bf, proj_b, (float*)d_out,
                                         NPIX, CDIM, CDIM, 2);
}

// Round 11
// 157.287 us; speedup vs baseline: 1.4362x; 1.0407x over previous
//
#include <hip/hip_runtime.h>
#include <stdint.h>

typedef __attribute__((ext_vector_type(4))) float f32x4;
typedef __attribute__((ext_vector_type(8))) short bf16x8;
typedef __attribute__((ext_vector_type(8))) unsigned short u16x8;
typedef __attribute__((ext_vector_type(4))) unsigned short u16x4;

#define NPIX 100352      // 32*56*56
#define CDIM 256
#define QKVN 768
#define HWDIM 56

__device__ __forceinline__ unsigned short f2bf(float f) {
  union { float f; unsigned int u; } cv; cv.f = f;
  unsigned int u = cv.u;
  unsigned int r = (u + 0x7FFFu + ((u >> 16) & 1u)) >> 16;
  return (unsigned short)r;
}
__device__ __forceinline__ float bf2f(unsigned short h) {
  union { unsigned int u; float f; } cv; cv.u = ((unsigned int)h) << 16;
  return cv.f;
}

// ---------------- Wqkv -> fragment-ordered bf16 table ----------------
// wtab base for (mat,h,ks,wsel,lane) = ((((mat*8+h)*8+ks)*2+wsel)*64+lane)*8
// holds W[mat*256 + h*32 + wsel*16 + (lane&15)][ks*32 + (lane>>4)*8 .. +8]
__global__ __launch_bounds__(256) void wqkv_pre(const float* __restrict__ w,
                                                unsigned short* __restrict__ wtab) {
  int e8 = blockIdx.x * 256 + threadIdx.x;   // 24576 total
  int l = e8 & 63;
  int t1 = e8 >> 6;
  int wsel = t1 & 1;
  int ks = (t1 >> 1) & 7;
  int h = (t1 >> 4) & 7;
  int m = t1 >> 7;          // 0..2
  int row = m * 256 + h * 32 + wsel * 16 + (l & 15);
  int col = ks * 32 + (l >> 4) * 8;
  const float4* src = reinterpret_cast<const float4*>(w + (size_t)row * 256 + col);
  float4 a = src[0], b = src[1];
  u16x8 r;
  r[0] = f2bf(a.x); r[1] = f2bf(a.y); r[2] = f2bf(a.z); r[3] = f2bf(a.w);
  r[4] = f2bf(b.x); r[5] = f2bf(b.y); r[6] = f2bf(b.z); r[7] = f2bf(b.w);
  *reinterpret_cast<u16x8*>(wtab + (size_t)e8 * 8) = r;
}

// ---------------- Wproj -> fragment-ordered bf16 table (B-operand) ----------------
// wptab base for (h,ks,wsel,lane) = (((h*8+ks)*2+wsel)*64+lane)*8
// holds Wp[h*32 + wsel*16 + (lane&15)][ks*32 + (lane>>4)*8 .. +8]
__global__ __launch_bounds__(256) void wproj_pre(const float* __restrict__ w,
                                                 unsigned short* __restrict__ wptab) {
  int e8 = blockIdx.x * 256 + threadIdx.x;   // 8192 total
  int l = e8 & 63;
  int t1 = e8 >> 6;
  int wsel = t1 & 1;
  int ks = (t1 >> 1) & 7;
  int h = (t1 >> 4) & 7;
  int row = h * 32 + wsel * 16 + (l & 15);
  int col = ks * 32 + (l >> 4) * 8;
  const float4* src = reinterpret_cast<const float4*>(w + (size_t)row * 256 + col);
  float4 a = src[0], b = src[1];
  u16x8 r;
  r[0] = f2bf(a.x); r[1] = f2bf(a.y); r[2] = f2bf(a.z); r[3] = f2bf(a.w);
  r[4] = f2bf(b.x); r[5] = f2bf(b.y); r[6] = f2bf(b.z); r[7] = f2bf(b.w);
  *reinterpret_cast<u16x8*>(wptab + (size_t)e8 * 8) = r;
}

// ---------------- bias+mask table precompute ----------------
__global__ __launch_bounds__(256) void bias_pre(const float* __restrict__ table,
                                                unsigned short* __restrict__ bt) {
  int e = blockIdx.x * 256 + threadIdx.x;       // 131072 total
  int r  = e & 3;
  int fr = (e >> 2) & 15;
  int q  = (e >> 6) & 3;
  int c2 = (e >> 8) & 3;
  int jf = (e >> 10) & 3;
  int h  = (e >> 12) & 7;
  int cls = (e >> 15) & 3;
  int j = jf * 16 + q * 4 + r;
  int i = c2 * 16 + fr;
  float v;
  if (j > 48 || i > 48) {
    v = -1e30f;
  } else {
    int bh = cls >> 1, bw = cls & 1;
    int iwi = i / 7, iwj = i % 7;
    int jwi = j / 7, jwj = j % 7;
    int ireg = (bh ? ((iwi < 4) ? 1 : 2) : 0) * 3 + (bw ? ((iwj < 4) ? 1 : 2) : 0);
    int jreg = (bh ? ((jwi < 4) ? 1 : 2) : 0) * 3 + (bw ? ((jwj < 4) ? 1 : 2) : 0);
    float m = (ireg == jreg) ? 0.f : -100.f;
    v = table[((iwi - jwi + 6) * 13 + (iwj - jwj + 6)) * 8 + h] + m;
  }
  bt[e] = f2bf(v);
}

// ---------------- fully fused: QKV GEMM + shifted-window attention + proj GEMM ----------------
// block = window (512 threads, 8 waves = 8 heads); 2 blocks/CU (LDS-limited)
__global__ __launch_bounds__(512, 2) void fused_attn(
    const float* __restrict__ x,              // [NPIX][256] fp32, pixel order
    const unsigned short* __restrict__ wtab,  // fragment-ordered Wqkv bf16
    const float* __restrict__ bqkv,           // [768]
    const unsigned short* __restrict__ btab,  // [4][8][4096] bf16
    const unsigned short* __restrict__ wptab, // fragment-ordered Wproj bf16
    const float* __restrict__ bproj,          // [256]
    float* __restrict__ out)                  // [NPIX][256] fp32, pixel order
{
  const int win = blockIdx.x;
  const int b = win >> 6;
  const int gi = (win >> 3) & 7;
  const int gj = win & 7;
  const int t = threadIdx.x;
  const int head = t >> 6;
  const int lane = t & 63;
  const int fr = lane & 15;
  const int q = lane >> 4;

  __shared__ unsigned short x_s[49 * 256];    // x window bf16, XOR-swizzled rows; reused as out_s
  __shared__ unsigned short Vt[8][32 * 70];   // per head Vt[d][j], stride 70
  __shared__ int pix_s[64];

  if (t < 64) {
    int idx = (t < 49) ? t : 48;
    int wi = idx / 7, wj = idx - (idx / 7) * 7;
    int hs = gi * 7 + wi, ws2 = gj * 7 + wj;
    int ph = hs + 3; if (ph >= HWDIM) ph -= HWDIM;
    int pw = ws2 + 3; if (pw >= HWDIM) pw -= HWDIM;
    pix_s[t] = (b * HWDIM + ph) * HWDIM + pw;
  }
  __syncthreads();

  // byte offset into x_s/out_s for (row, bytecol): XOR swizzle -> ~2-way banks
  #define XS(row, bc) ((unsigned)((row) * 512 + (((bc)) ^ (((row) & 7) << 4))))

  // ---- stage x window -> LDS bf16 (49 x 256, swizzled) ----
  for (int u = t; u < 49 * 32; u += 512) {
    int pix = u >> 5, seg = u & 31;
    const float4* src = reinterpret_cast<const float4*>(x + (size_t)pix_s[pix] * CDIM + seg * 8);
    float4 a = src[0], c = src[1];
    u16x8 r;
    r[0] = f2bf(a.x); r[1] = f2bf(a.y); r[2] = f2bf(a.z); r[3] = f2bf(a.w);
    r[4] = f2bf(c.x); r[5] = f2bf(c.y); r[6] = f2bf(c.z); r[7] = f2bf(c.w);
    *reinterpret_cast<u16x8*>((char*)x_s + XS(pix, seg * 16)) = r;
  }
  __syncthreads();

  const int cls = (((gi == 7) ? 1 : 0) << 1) | ((gj == 7) ? 1 : 0);
  const unsigned short* bth = btab + (((cls << 3) | head) << 12);
  unsigned short* VtW = Vt[head];
  const int srcA = ((q & 1) << 5) + fr;
  const int srcB = srcA + 16;
  const bool hi = (q >= 2);

  #define PACK_MAT(pkm)                                                                \
  { _Pragma("unroll") for (int d = 0; d < 2; ++d)                                      \
      _Pragma("unroll") for (int p2 = 0; p2 < 4; ++p2) {                               \
        pkm[d][p2][0] = (unsigned)f2bf(acc[d][p2][0]) | ((unsigned)f2bf(acc[d][p2][1]) << 16); \
        pkm[d][p2][1] = (unsigned)f2bf(acc[d][p2][2]) | ((unsigned)f2bf(acc[d][p2][3]) << 16); \
      } }

  #define BUILD_FRAG(pkm, p2, dst)                                                     \
  { unsigned a0 = (unsigned)__shfl((int)pkm[0][p2][0], srcA);                          \
    unsigned a1 = (unsigned)__shfl((int)pkm[0][p2][1], srcA);                          \
    unsigned a2 = (unsigned)__shfl((int)pkm[0][p2][0], srcB);                          \
    unsigned a3 = (unsigned)__shfl((int)pkm[0][p2][1], srcB);                          \
    unsigned b0 = (unsigned)__shfl((int)pkm[1][p2][0], srcA);                          \
    unsigned b1 = (unsigned)__shfl((int)pkm[1][p2][1], srcA);                          \
    unsigned b2 = (unsigned)__shfl((int)pkm[1][p2][0], srcB);                          \
    unsigned b3 = (unsigned)__shfl((int)pkm[1][p2][1], srcB);                          \
    union { unsigned u[4]; bf16x8 v; } uf;                                             \
    uf.u[0] = hi ? b0 : a0; uf.u[1] = hi ? b1 : a1;                                    \
    uf.u[2] = hi ? b2 : a2; uf.u[3] = hi ? b3 : a3;                                    \
    dst = uf.v; }

  // ---- QKV via one shared loop body: mat 2=V, 1=K, 0=Q ----
  unsigned pkk[2][4][2], pkq[2][4][2];
  {
    f32x4 acc[2][4];
    #pragma unroll 1
    for (int m = 0; m < 3; ++m) {
      const int mat = 2 - m;
      #pragma unroll
      for (int d = 0; d < 2; ++d)
        #pragma unroll
        for (int p2 = 0; p2 < 4; ++p2)
          acc[d][p2] = (f32x4){0.f, 0.f, 0.f, 0.f};
      #pragma unroll
      for (int ks = 0; ks < 8; ++ks) {
        const unsigned short* wb = wtab + (size_t)((((mat * 8 + head) * 8 + ks) * 128 + lane) * 8);
        bf16x8 wf0 = *reinterpret_cast<const bf16x8*>(wb);
        bf16x8 wf1 = *reinterpret_cast<const bf16x8*>(wb + 512);
        int bc = ks * 64 + q * 16;
        bf16x8 xf0 = *reinterpret_cast<const bf16x8*>((const char*)x_s + XS(fr, bc));
        bf16x8 xf1 = *reinterpret_cast<const bf16x8*>((const char*)x_s + XS(16 + fr, bc));
        bf16x8 xf2 = *reinterpret_cast<const bf16x8*>((const char*)x_s + XS(32 + fr, bc));
        bf16x8 x3r = *reinterpret_cast<const bf16x8*>((const char*)x_s + XS(48, bc));
        bf16x8 xf3 = (fr == 0) ? x3r : (bf16x8){0, 0, 0, 0, 0, 0, 0, 0};
        acc[0][0] = __builtin_amdgcn_mfma_f32_16x16x32_bf16(wf0, xf0, acc[0][0], 0, 0, 0);
        acc[0][1] = __builtin_amdgcn_mfma_f32_16x16x32_bf16(wf0, xf1, acc[0][1], 0, 0, 0);
        acc[0][2] = __builtin_amdgcn_mfma_f32_16x16x32_bf16(wf0, xf2, acc[0][2], 0, 0, 0);
        acc[0][3] = __builtin_amdgcn_mfma_f32_16x16x32_bf16(wf0, xf3, acc[0][3], 0, 0, 0);
        acc[1][0] = __builtin_amdgcn_mfma_f32_16x16x32_bf16(wf1, xf0, acc[1][0], 0, 0, 0);
        acc[1][1] = __builtin_amdgcn_mfma_f32_16x16x32_bf16(wf1, xf1, acc[1][1], 0, 0, 0);
        acc[1][2] = __builtin_amdgcn_mfma_f32_16x16x32_bf16(wf1, xf2, acc[1][2], 0, 0, 0);
        acc[1][3] = __builtin_amdgcn_mfma_f32_16x16x32_bf16(wf1, xf3, acc[1][3], 0, 0, 0);
      }
      #pragma unroll
      for (int d = 0; d < 2; ++d) {
        f32x4 bv = *reinterpret_cast<const f32x4*>(bqkv + mat * 256 + head * 32 + d * 16 + q * 4);
        acc[d][0] += bv; acc[d][1] += bv; acc[d][2] += bv; acc[d][3] += bv;
      }
      if (mat == 2) {
        #pragma unroll
        for (int d = 0; d < 2; ++d)
          #pragma unroll
          for (int p2 = 0; p2 < 4; ++p2)
            #pragma unroll
            for (int r = 0; r < 4; ++r)
              VtW[(d * 16 + q * 4 + r) * 70 + p2 * 16 + fr] = f2bf(acc[d][p2][r]);
      } else if (mat == 1) {
        PACK_MAT(pkk);
      } else {
        PACK_MAT(pkq);
      }
    }
  }

  bf16x8 qf[4];
  BUILD_FRAG(pkq, 0, qf[0]); BUILD_FRAG(pkq, 1, qf[1]);
  BUILD_FRAG(pkq, 2, qf[2]); BUILD_FRAG(pkq, 3, qf[3]);

  // ---- S^T + softmax ----
  const float scale = 0.17677669529663687f;  // 1/sqrt(32)
  u16x4 aw[2][4];
  #pragma unroll
  for (int c2 = 0; c2 < 4; ++c2)
    aw[0][c2] = *reinterpret_cast<const u16x4*>(bth + (c2 << 8) + (q << 6) + (fr << 2));
  float colsum[4] = {0.f, 0.f, 0.f, 0.f};
  unsigned pk[4][4][2];
  #pragma unroll
  for (int jf = 0; jf < 4; ++jf) {
    bf16x8 kfj;
    BUILD_FRAG(pkk, jf, kfj);
    f32x4 sacc[4];
    #pragma unroll
    for (int c2 = 0; c2 < 4; ++c2) {
      f32x4 z = {0.f, 0.f, 0.f, 0.f};
      sacc[c2] = __builtin_amdgcn_mfma_f32_16x16x32_bf16(kfj, qf[c2], z, 0, 0, 0);
    }
    if (jf < 3) {
      #pragma unroll
      for (int c2 = 0; c2 < 4; ++c2)
        aw[(jf + 1) & 1][c2] = *reinterpret_cast<const u16x4*>(
            bth + (((jf + 1) * 4 + c2) << 8) + (q << 6) + (fr << 2));
    }
    #pragma unroll
    for (int c2 = 0; c2 < 4; ++c2) {
      float ev[4];
      #pragma unroll
      for (int r = 0; r < 4; ++r) {
        float val = fmaf(sacc[c2][r], scale, bf2f(aw[jf & 1][c2][r]));
        ev[r] = __expf(val);
        colsum[c2] += ev[r];
      }
      unsigned h0 = f2bf(ev[0]), h1 = f2bf(ev[1]);
      unsigned h2 = f2bf(ev[2]), h3 = f2bf(ev[3]);
      pk[jf][c2][0] = h0 | (h1 << 16);
      pk[jf][c2][1] = h2 | (h3 << 16);
    }
  }
  float rinv[4];
  #pragma unroll
  for (int c2 = 0; c2 < 4; ++c2) {
    float s = colsum[c2];
    s += __shfl_xor(s, 16);
    s += __shfl_xor(s, 32);
    rinv[c2] = 1.0f / s;
  }

  // ---- PV: attnT[d][i] = sum_j Vt[d][j] * P^T[j][i] ----
  f32x4 outT[2][4] = {};
  #pragma unroll
  for (int kb = 0; kb < 2; ++kb) {
    bf16x8 vf0 = *reinterpret_cast<const bf16x8*>(&VtW[(fr)      * 70 + kb * 32 + q * 8]);
    bf16x8 vf1 = *reinterpret_cast<const bf16x8*>(&VtW[(16 + fr) * 70 + kb * 32 + q * 8]);
    #pragma unroll
    for (int c2 = 0; c2 < 4; ++c2) {
      bf16x8 pf;
      {
        unsigned a0 = (unsigned)__shfl((int)pk[2 * kb][c2][0], srcA);
        unsigned a1 = (unsigned)__shfl((int)pk[2 * kb][c2][1], srcA);
        unsigned a2 = (unsigned)__shfl((int)pk[2 * kb][c2][0], srcB);
        unsigned a3 = (unsigned)__shfl((int)pk[2 * kb][c2][1], srcB);
        unsigned b0 = (unsigned)__shfl((int)pk[2 * kb + 1][c2][0], srcA);
        unsigned b1 = (unsigned)__shfl((int)pk[2 * kb + 1][c2][1], srcA);
        unsigned b2 = (unsigned)__shfl((int)pk[2 * kb + 1][c2][0], srcB);
        unsigned b3 = (unsigned)__shfl((int)pk[2 * kb + 1][c2][1], srcB);
        union { unsigned u[4]; bf16x8 v; } pfv;
        pfv.u[0] = hi ? b0 : a0;
        pfv.u[1] = hi ? b1 : a1;
        pfv.u[2] = hi ? b2 : a2;
        pfv.u[3] = hi ? b3 : a3;
        pf = pfv.v;
      }
      outT[0][c2] = __builtin_amdgcn_mfma_f32_16x16x32_bf16(vf0, pf, outT[0][c2], 0, 0, 0);
      outT[1][c2] = __builtin_amdgcn_mfma_f32_16x16x32_bf16(vf1, pf, outT[1][c2], 0, 0, 0);
    }
  }

  // ---- stage attnout in LDS (reuse x_s region; bf16, swizzled) ----
  unsigned short* out_s = x_s;
  __syncthreads();   // all waves done reading x_s / own Vt
  #pragma unroll
  for (int c2 = 0; c2 < 4; ++c2) {
    int i = c2 * 16 + fr;
    if (i < 49) {
      float rv = rinv[c2];
      #pragma unroll
      for (int nt = 0; nt < 2; ++nt) {
        f32x4 o = outT[nt][c2];
        u16x4 pkd;
        pkd[0] = f2bf(o[0] * rv); pkd[1] = f2bf(o[1] * rv);
        pkd[2] = f2bf(o[2] * rv); pkd[3] = f2bf(o[3] * rv);
        *reinterpret_cast<u16x4*>((char*)out_s + XS(i, head * 64 + nt * 32 + q * 8)) = pkd;
      }
    }
  }
  __syncthreads();   // out_s complete (proj consumes all heads' columns)

  // ---- fused proj: D[pix][dim] = attnout(49x256) x Wproj^T slice (32 cols/head) ----
  {
    f32x4 pacc[2][4];   // [wsel][p2]
    #pragma unroll
    for (int w = 0; w < 2; ++w)
      #pragma unroll
      for (int p2 = 0; p2 < 4; ++p2)
        pacc[w][p2] = (f32x4){0.f, 0.f, 0.f, 0.f};
    #pragma unroll
    for (int ks = 0; ks < 8; ++ks) {
      const unsigned short* wb = wptab + (size_t)((((head * 8 + ks) * 2) * 64 + lane) * 8);
      bf16x8 wp0 = *reinterpret_cast<const bf16x8*>(wb);
      bf16x8 wp1 = *reinterpret_cast<const bf16x8*>(wb + 512);
      int bc = ks * 64 + q * 16;
      bf16x8 of0 = *reinterpret_cast<const bf16x8*>((const char*)out_s + XS(fr, bc));
      bf16x8 of1 = *reinterpret_cast<const bf16x8*>((const char*)out_s + XS(16 + fr, bc));
      bf16x8 of2 = *reinterpret_cast<const bf16x8*>((const char*)out_s + XS(32 + fr, bc));
      bf16x8 o3r = *reinterpret_cast<const bf16x8*>((const char*)out_s + XS(48, bc));
      bf16x8 of3 = (fr == 0) ? o3r : (bf16x8){0, 0, 0, 0, 0, 0, 0, 0};
      pacc[0][0] = __builtin_amdgcn_mfma_f32_16x16x32_bf16(of0, wp0, pacc[0][0], 0, 0, 0);
      pacc[0][1] = __builtin_amdgcn_mfma_f32_16x16x32_bf16(of1, wp0, pacc[0][1], 0, 0, 0);
      pacc[0][2] = __builtin_amdgcn_mfma_f32_16x16x32_bf16(of2, wp0, pacc[0][2], 0, 0, 0);
      pacc[0][3] = __builtin_amdgcn_mfma_f32_16x16x32_bf16(of3, wp0, pacc[0][3], 0, 0, 0);
      pacc[1][0] = __builtin_amdgcn_mfma_f32_16x16x32_bf16(of0, wp1, pacc[1][0], 0, 0, 0);
      pacc[1][1] = __builtin_amdgcn_mfma_f32_16x16x32_bf16(of1, wp1, pacc[1][1], 0, 0, 0);
      pacc[1][2] = __builtin_amdgcn_mfma_f32_16x16x32_bf16(of2, wp1, pacc[1][2], 0, 0, 0);
      pacc[1][3] = __builtin_amdgcn_mfma_f32_16x16x32_bf16(of3, wp1, pacc[1][3], 0, 0, 0);
    }
    // bias + store: lane holds dim = head*32 + w*16 + fr, pix = p2*16 + q*4 + r
    float bb0 = bproj[head * 32 + fr];
    float bb1 = bproj[head * 32 + 16 + fr];
    #pragma unroll
    for (int p2 = 0; p2 < 4; ++p2) {
      #pragma unroll
      for (int r = 0; r < 4; ++r) {
        int pix = p2 * 16 + q * 4 + r;
        if (pix < 49) {
          float* op = out + (size_t)pix_s[pix] * CDIM + head * 32 + fr;
          op[0]  = pacc[0][p2][r] + bb0;
          op[16] = pacc[1][p2][r] + bb1;
        }
      }
    }
  }
  #undef PACK_MAT
  #undef BUILD_FRAG
  #undef XS
}

// ---------------- launch ----------------
extern "C" void kernel_launch(void* const* d_in, const int* in_sizes, int n_in,
                              void* d_out, int out_size, void* d_ws, size_t ws_size,
                              hipStream_t stream) {
  const float* x      = (const float*)d_in[0];
  const float* qkv_w  = (const float*)d_in[1];
  const float* qkv_b  = (const float*)d_in[2];
  const float* proj_w = (const float*)d_in[3];
  const float* proj_b = (const float*)d_in[4];
  const float* table  = (const float*)d_in[5];

  char* ws = (char*)d_ws;
  unsigned short* btab  = (unsigned short*)ws;               // 262,144 B
  unsigned short* wtab  = (unsigned short*)(ws + 262144);    // 393,216 B
  unsigned short* wptab = (unsigned short*)(ws + 655360);    // 131,072 B

  bias_pre<<<512, 256, 0, stream>>>(table, btab);
  wqkv_pre<<<96, 256, 0, stream>>>(qkv_w, wtab);
  wproj_pre<<<32, 256, 0, stream>>>(proj_w, wptab);

  fused_attn<<<2048, 512, 0, stream>>>(x, wtab, qkv_b, btab, wptab, proj_b,
                                       (float*)d_out);
}